// Round 9
// baseline (403.861 us; speedup 1.0000x reference)
//
#include <hip/hip_runtime.h>
#include <hip/hip_bf16.h>

#define E 256
#define H 8
#define HD 32
#define T 768
#define B 4
#define BH 32
// segments: L=[0,300), A=[300,550), V=[550,768)

__device__ __forceinline__ float b2f(__hip_bfloat16 x) { return __bfloat162float(x); }

// dtype-agnostic scalar load: f32 ? float : bf16
__device__ __forceinline__ float ldu(const void* p, size_t i, int f32) {
    if (f32) return ((const float*)p)[i];
    return b2f(((const __hip_bfloat16*)p)[i]);
}

// ---------------------------------------------------------------------------
// Kernel 0: input dtype detection (fp32 read as bf16 -> garbage exponents).
// ---------------------------------------------------------------------------
__global__ void detect_kernel(const unsigned short* __restrict__ q,
                              int* __restrict__ flag) {
    if (threadIdx.x == 0 && blockIdx.x == 0) {
        int f32 = 0;
        for (int i = 0; i < 256; ++i) {
            unsigned int bits = ((unsigned int)q[i]) << 16;
            float v = __uint_as_float(bits);
            if (!(v == v) || fabsf(v) > 1e4f) f32 = 1;
        }
        *flag = f32;
    }
}

// ---------------------------------------------------------------------------
// Kernel 1: QKV projection as a tiled GEMM. (proven round-4)
// ---------------------------------------------------------------------------
__global__ __launch_bounds__(256) void qkv_gemm_kernel(
    const void* query, const void* key, const void* value,
    const void* w, const void* bias, const int* __restrict__ flag,
    float* __restrict__ qws, float* __restrict__ kws, float* __restrict__ vws)
{
    int f32 = *flag;
    int bx = blockIdx.x;              // 0..11 col tiles
    int by = blockIdx.y;              // 0..47 row tiles
    int sec = bx >> 2;                // 0=q, 1=k, 2=v
    const void* X = (sec == 0) ? query : (sec == 1) ? key : value;
    int colbase = bx * 64;
    int rowbase = by * 64;
    int tid = threadIdx.x;
    int tx = tid & 15, ty = tid >> 4;
    __shared__ float As[64][33];
    __shared__ float Bs[32][65];
    float acc[4][4] = {};

    for (int kb = 0; kb < 8; ++kb) {
        __syncthreads();
        #pragma unroll
        for (int l = 0; l < 8; ++l) {
            int idx = l * 256 + tid;
            int r = idx >> 5, c = idx & 31;
            As[r][c] = ldu(X, (size_t)(rowbase + r) * 256 + kb * 32 + c, f32);
            int n = idx >> 5, kk = idx & 31;
            Bs[kk][n] = ldu(w, (size_t)(colbase + n) * 256 + kb * 32 + kk, f32);
        }
        __syncthreads();
        #pragma unroll 8
        for (int kk = 0; kk < 32; ++kk) {
            float av[4], bv[4];
            #pragma unroll
            for (int u = 0; u < 4; ++u) av[u] = As[ty * 4 + u][kk];
            #pragma unroll
            for (int v = 0; v < 4; ++v) bv[v] = Bs[kk][tx * 4 + v];
            #pragma unroll
            for (int u = 0; u < 4; ++u)
                #pragma unroll
                for (int v = 0; v < 4; ++v)
                    acc[u][v] += av[u] * bv[v];
        }
    }
    float* dst = (sec == 0) ? qws : (sec == 1) ? kws : vws;
    #pragma unroll
    for (int u = 0; u < 4; ++u)
        #pragma unroll
        for (int v = 0; v < 4; ++v) {
            int r = rowbase + ty * 4 + u;          // t*B + b
            int cg = colbase + tx * 4 + v;         // 0..767
            float val = acc[u][v] + ldu(bias, cg, f32);
            if (sec == 0) val *= 0.17677669529663687f;  // HD^-0.5
            int e_local = cg & 255;
            int h = e_local >> 5, hd = e_local & 31;
            int t = r >> 2, b = r & 3;
            dst[((size_t)((b * H + h) * T + t)) * HD + hd] = val;
        }
}

// ---------------------------------------------------------------------------
// Kernel 2: t-tiled attention, RETILED round-9: 32-row t-tiles, grid (24,32)
// = 768 blocks (~3/CU vs 1.5 before), LDS 43->30KB. Thread map: tx=s-group,
// ty 0..15 = 2 t-rows each. e_s write banks now 2-way (free) vs 8-way.
// ---------------------------------------------------------------------------
#define PV_BODY(SEG)                                                     \
    {                                                                    \
        float ev0 = e_s[ty * 2 + 0][ss];                                 \
        float ev1 = e_s[ty * 2 + 1][ss];                                 \
        float v0 = v_s[ss][tx * 2], v1 = v_s[ss][tx * 2 + 1];            \
        pacc[SEG][0][0] += ev0 * v0; pacc[SEG][0][1] += ev0 * v1;        \
        pacc[SEG][1][0] += ev1 * v0; pacc[SEG][1][1] += ev1 * v1;        \
    }

__global__ __launch_bounds__(256) void attn_tiled_kernel(
    const float* __restrict__ qws, const float* __restrict__ kws,
    const float* __restrict__ vws, float* __restrict__ O)
{
    int tile = blockIdx.x;       // 0..23
    int bh   = blockIdx.y;       // 0..31
    int t0 = tile * 32;
    int tid = threadIdx.x;
    int tx = tid & 15, ty = tid >> 4;   // ty 0..15

    __shared__ float q_s[32][33];
    __shared__ float k_s[64][33];
    __shared__ float v_s[64][33];
    __shared__ float e_s[32][65];
    __shared__ float S_s[32][3];

    const float* qbase = qws + ((size_t)bh * T + t0) * HD;
    #pragma unroll
    for (int l = 0; l < 4; ++l) {
        int idx = l * 256 + tid;
        q_s[idx >> 5][idx & 31] = qbase[idx];
    }

    float pacc[3][2][2] = {};   // [seg][u: t-row][w: hd pair]
    float ssum[3][2] = {};      // [seg][u] partial exp-sums over own s-cols

    const float* kbase = kws + (size_t)bh * T * HD;
    const float* vbase = vws + (size_t)bh * T * HD;

    for (int ch = 0; ch < 12; ++ch) {
        int base = ch * 64;
        __syncthreads();    // all waves done reading k_s/v_s/e_s of prev chunk
        #pragma unroll
        for (int l = 0; l < 8; ++l) {
            int idx = l * 256 + tid;
            k_s[idx >> 5][idx & 31] = kbase[(size_t)base * HD + idx];
            v_s[idx >> 5][idx & 31] = vbase[(size_t)base * HD + idx];
        }
        __syncthreads();

        // Phase A: 2x4 score tile, K=32, then exp -> e_s + per-seg sums.
        float sc[2][4] = {};
        #pragma unroll 8
        for (int kk = 0; kk < 32; ++kk) {
            float qv[2], kv[4];
            #pragma unroll
            for (int u = 0; u < 2; ++u) qv[u] = q_s[ty * 2 + u][kk];
            #pragma unroll
            for (int vv = 0; vv < 4; ++vv) kv[vv] = k_s[tx * 4 + vv][kk];
            #pragma unroll
            for (int u = 0; u < 2; ++u)
                #pragma unroll
                for (int vv = 0; vv < 4; ++vv)
                    sc[u][vv] += qv[u] * kv[vv];
        }
        #pragma unroll
        for (int u = 0; u < 2; ++u)
            #pragma unroll
            for (int vv = 0; vv < 4; ++vv) {
                float e = __expf(sc[u][vv]);
                int sg = base + tx * 4 + vv;
                if (sg < 300) ssum[0][u] += e;
                else if (sg < 550) ssum[1][u] += e;
                else ssum[2][u] += e;
                e_s[ty * 2 + u][tx * 4 + vv] = e;
            }
        __syncthreads();

        // Phase B: P[seg] += E @ V, segment subranges (wave-uniform bounds).
        int e0 = min(max(300 - base, 0), 64);
        int e1 = min(max(550 - base, 0), 64);
        for (int ss = 0; ss < e0; ++ss) PV_BODY(0)
        for (int ss = e0; ss < e1; ++ss) PV_BODY(1)
        for (int ss = e1; ss < 64; ++ss) PV_BODY(2)
    }

    // Reduce ssum across tx (16 threads share each t-row group).
    #pragma unroll
    for (int sg = 0; sg < 3; ++sg)
        #pragma unroll
        for (int u = 0; u < 2; ++u) {
            float v = ssum[sg][u];
            v += __shfl_down(v, 8, 16);
            v += __shfl_down(v, 4, 16);
            v += __shfl_down(v, 2, 16);
            v += __shfl_down(v, 1, 16);
            if (tx == 0) S_s[ty * 2 + u][sg] = v;
        }
    __syncthreads();

    // Epilogue: 7 branch outputs for this thread's 2 t-rows x 2 hd.
    int b = bh >> 3, h = bh & 7;
    const int masks[7] = {7, 3, 5, 6, 1, 2, 4};  // LAV,LA,LV,AV,L,A,V
    #pragma unroll
    for (int u = 0; u < 2; ++u) {
        int t = t0 + ty * 2 + u;
        int g = (t < 300) ? 0 : (t < 550 ? 1 : 2);
        float S0 = S_s[ty * 2 + u][0], S1 = S_s[ty * 2 + u][1], S2 = S_s[ty * 2 + u][2];
        float p00 = pacc[0][u][0], p01 = pacc[0][u][1];
        float p10 = pacc[1][u][0], p11 = pacc[1][u][1];
        float p20 = pacc[2][u][0], p21 = pacc[2][u][1];
        float* orow = O + (size_t)(t * B + b) * 1792 + h * 32 + tx * 2;
        #pragma unroll
        for (int i = 0; i < 7; ++i) {
            int m = masks[i];
            float n0 = 0.f, n1 = 0.f, den = 0.f;
            if (m & 1) { n0 += p00; n1 += p01; den += S0; }
            if (m & 2) { n0 += p10; n1 += p11; den += S1; }
            if (m & 4) { n0 += p20; n1 += p21; den += S2; }
            float r = 1.f / den;
            int live = (m >> g) & 1;
            orow[i * 256]     = live ? n0 * r : 0.f;
            orow[i * 256 + 1] = live ? n1 * r : 0.f;
        }
    }
}

// ---------------------------------------------------------------------------
// Weight combination: D_i = (final_w @ G_i @ out_w[i])^T stacked as (1792,256).
// ---------------------------------------------------------------------------
__device__ __forceinline__ float gsum_load(int i, int r2, int r,
                                           const void* sl, const void* sa,
                                           const void* sv, int f32)
{
    size_t base = (size_t)r2 * 1024;
    switch (i) {
        case 0: return ldu(sl, base + r, f32) + ldu(sa, base + r, f32) + ldu(sv, base + r, f32);
        case 1: return ldu(sl, base + 256 + r, f32) + ldu(sa, base + 256 + r, f32);
        case 2: return ldu(sl, base + 512 + r, f32) + ldu(sv, base + 256 + r, f32);
        case 3: return ldu(sa, base + 512 + r, f32) + ldu(sv, base + 512 + r, f32);
        case 4: return ldu(sl, base + 768 + r, f32);
        case 5: return ldu(sa, base + 768 + r, f32);
        default: return ldu(sv, base + 768 + r, f32);
    }
}

// Mtmp_i = G_i @ out_w[i]    (proven round-2)
__global__ __launch_bounds__(256) void wcomb1_kernel(
    const void* sl, const void* sa, const void* sv, const void* outw,
    const int* __restrict__ flag, float* __restrict__ Mtmp)
{
    int f32 = *flag;
    int bid = blockIdx.x;
    int i = bid >> 8, r2 = bid & 255;
    int c = threadIdx.x;
    __shared__ float g[256];
    g[c] = gsum_load(i, r2, c, sl, sa, sv, f32);
    __syncthreads();
    float acc = 0.f;
    for (int r = 0; r < 256; ++r)
        acc += g[r] * ldu(outw, (size_t)i * 65536 + r * 256 + c, f32);
    Mtmp[(size_t)i * 65536 + r2 * 256 + c] = acc;
}

// Dstack_i = Mtmp_i^T @ final_w^T as tiled GEMM (proven round-7).
// Dstack[(i*256+c)][e] = sum_j Mtmp[i][j][c] * finalw[e][j]
__global__ __launch_bounds__(256) void wcomb2_gemm_kernel(
    const float* __restrict__ Mtmp, const void* finalw,
    const int* __restrict__ flag, float* __restrict__ Dstack)
{
    int f32 = *flag;
    int bx = blockIdx.x;   // col tile 0..3 (e)
    int by = blockIdx.y;   // row tile 0..3 (c)
    int i  = blockIdx.z;   // branch 0..6
    int tid = threadIdx.x;
    int tx = tid & 15, ty = tid >> 4;
    int colbase = bx * 64, rowbase = by * 64;
    __shared__ float As[64][33];   // Mtmp^T [c][j]
    __shared__ float Bs[32][65];   // finalw^T [j][e]
    float acc[4][4] = {};

    for (int kb = 0; kb < 8; ++kb) {
        __syncthreads();
        #pragma unroll
        for (int l = 0; l < 8; ++l) {
            int idx = l * 256 + tid;
            int r = idx & 63, kk = idx >> 6;      // r contiguous -> coalesced
            As[r][kk] = Mtmp[(size_t)i * 65536 + (kb * 32 + kk) * 256 + rowbase + r];
            int n = idx >> 5, k2 = idx & 31;      // k2 contiguous -> coalesced
            Bs[k2][n] = ldu(finalw, (size_t)(colbase + n) * 256 + kb * 32 + k2, f32);
        }
        __syncthreads();
        #pragma unroll 8
        for (int kk = 0; kk < 32; ++kk) {
            float av[4], bv[4];
            #pragma unroll
            for (int u = 0; u < 4; ++u) av[u] = As[ty * 4 + u][kk];
            #pragma unroll
            for (int v = 0; v < 4; ++v) bv[v] = Bs[kk][tx * 4 + v];
            #pragma unroll
            for (int u = 0; u < 4; ++u)
                #pragma unroll
                for (int v = 0; v < 4; ++v)
                    acc[u][v] += av[u] * bv[v];
        }
    }
    #pragma unroll
    for (int u = 0; u < 4; ++u)
        #pragma unroll
        for (int v = 0; v < 4; ++v) {
            int c = rowbase + ty * 4 + u, e = colbase + tx * 4 + v;
            Dstack[(size_t)(i * 256 + c) * 256 + e] = acc[u][v];
        }
}

// ---------------------------------------------------------------------------
// Bias path (proven round-5). c0 ALIASES Mtmp (dead after wcomb2).
// ws footprint unchanged from proven layout — do NOT grow it.
// ---------------------------------------------------------------------------
__global__ __launch_bounds__(256) void bias1_kernel(
    const void* sl, const void* sa, const void* sv, const void* outb,
    const void* slb, const void* sab, const void* svb,
    const int* __restrict__ flag, float* __restrict__ c0)
{
    int f32 = *flag;
    int r2 = blockIdx.x, m = threadIdx.x;
    __shared__ float red[256];
    float acc = 0.f;
    #pragma unroll
    for (int i = 0; i < 7; ++i)
        acc += ldu(outb, i * 256 + m, f32) * gsum_load(i, r2, m, sl, sa, sv, f32);
    red[m] = acc;
    __syncthreads();
    for (int s = 128; s > 0; s >>= 1) {
        if (m < s) red[m] += red[m + s];
        __syncthreads();
    }
    if (m == 0)
        c0[r2] = red[0] + ldu(slb, r2, f32) + ldu(sab, r2, f32) + ldu(svb, r2, f32);
}

__global__ __launch_bounds__(256) void bias2_kernel(
    const float* __restrict__ c0, const void* finalw, const void* finalb,
    const int* __restrict__ flag, float* __restrict__ d0)
{
    int f32 = *flag;
    int e = blockIdx.x, r = threadIdx.x;
    __shared__ float red[256];
    red[r] = c0[r] * ldu(finalw, (size_t)e * 256 + r, f32);
    __syncthreads();
    for (int s = 128; s > 0; s >>= 1) {
        if (r < s) red[r] += red[r + s];
        __syncthreads();
    }
    if (r == 0)
        d0[e] = red[0] + ldu(finalb, e, f32);
}

// ---------------------------------------------------------------------------
// Kernel 4: result = O (3072x1792) @ Dstack (1792x256) + d0 (proven round-8:
// 32x32 tiles, grid (8,96) = 768 blocks).
// ---------------------------------------------------------------------------
__global__ __launch_bounds__(256) void final_gemm_kernel(
    const float* __restrict__ O, const float* __restrict__ Dstack,
    const float* __restrict__ d0, const int* __restrict__ flag,
    void* __restrict__ outv)
{
    int f32 = *flag;
    int bx = blockIdx.x;   // col tile 0..7 (32 cols)
    int by = blockIdx.y;   // row tile 0..95 (32 rows = 8 t values)
    int tid = threadIdx.x;
    int tx = tid & 15, ty = tid >> 4;
    __shared__ float As[32][33];
    __shared__ float Bs[32][33];
    float acc[2][2] = {};

    int t0 = by * 8, t1 = t0 + 7;
    int g0 = (t0 < 300) ? 0 : (t0 < 550 ? 1 : 2);
    int g1 = (t1 < 300) ? 0 : (t1 < 550 ? 1 : 2);
    int activeset = (1 << g0) | (1 << g1);
    const int masks[7] = {7, 3, 5, 6, 1, 2, 4};
    int rowbase = by * 32, colbase = bx * 32;

    for (int i = 0; i < 7; ++i) {
        if (!(masks[i] & activeset)) continue;   // whole O block is zero
        for (int kb = 0; kb < 8; ++kb) {
            int cb = i * 256 + kb * 32;
            __syncthreads();
            #pragma unroll
            for (int l = 0; l < 4; ++l) {
                int idx = l * 256 + tid;
                int r = idx >> 5, c = idx & 31;
                As[r][c] = O[(size_t)(rowbase + r) * 1792 + cb + c];
                Bs[r][c] = Dstack[(size_t)(cb + r) * 256 + colbase + c];
            }
            __syncthreads();
            #pragma unroll 8
            for (int kk = 0; kk < 32; ++kk) {
                float a0 = As[ty * 2][kk], a1 = As[ty * 2 + 1][kk];
                float b0 = Bs[kk][tx * 2], b1 = Bs[kk][tx * 2 + 1];
                acc[0][0] += a0 * b0; acc[0][1] += a0 * b1;
                acc[1][0] += a1 * b0; acc[1][1] += a1 * b1;
            }
        }
    }
    #pragma unroll
    for (int u = 0; u < 2; ++u)
        #pragma unroll
        for (int v = 0; v < 2; ++v) {
            int r = rowbase + ty * 2 + u, c = colbase + tx * 2 + v;
            float val = acc[u][v] + d0[c];
            if (f32) ((float*)outv)[(size_t)r * 256 + c] = val;
            else ((__hip_bfloat16*)outv)[(size_t)r * 256 + c] = __float2bfloat16(val);
        }
}

// ---------------------------------------------------------------------------
extern "C" void kernel_launch(void* const* d_in, const int* in_sizes, int n_in,
                              void* d_out, int out_size, void* d_ws, size_t ws_size,
                              hipStream_t stream) {
    const void* query     = d_in[0];
    const void* key       = d_in[1];
    const void* value     = d_in[2];
    const void* in_proj_w = d_in[3];
    const void* in_proj_b = d_in[4];
    const void* out_w     = d_in[5];
    const void* out_b     = d_in[6];
    const void* s_l_w     = d_in[7];
    const void* s_l_b     = d_in[8];
    const void* s_a_w     = d_in[9];
    const void* s_a_b     = d_in[10];
    const void* s_v_w     = d_in[11];
    const void* s_v_b     = d_in[12];
    const void* final_w   = d_in[13];
    const void* final_b   = d_in[14];

    float* ws     = (float*)d_ws;
    float* qws    = ws;                 //   786432 f
    float* kws    = ws + 786432;        //   786432 f
    float* vws    = ws + 1572864;       //   786432 f
    float* O      = ws + 2359296;       //  5505024 f (3072 x 1792)
    float* Mtmp   = ws + 7864320;       //   458752 f
    float* Dstack = ws + 8323072;       //   458752 f (1792 x 256)
    float* d0     = ws + 8781824;       //      256 f
    int*   flag   = (int*)(ws + 8782080);  // 1 int — proven footprint HIGH-WATER
    float* c0     = Mtmp;               // ALIAS: Mtmp dead after wcomb2

    detect_kernel<<<1, 64, 0, stream>>>((const unsigned short*)query, flag);
    qkv_gemm_kernel<<<dim3(12, 48), 256, 0, stream>>>(query, key, value,
                                                      in_proj_w, in_proj_b, flag,
                                                      qws, kws, vws);
    wcomb1_kernel<<<7 * 256, 256, 0, stream>>>(s_l_w, s_a_w, s_v_w, out_w, flag, Mtmp);
    attn_tiled_kernel<<<dim3(24, 32), 256, 0, stream>>>(qws, kws, vws, O);
    wcomb2_gemm_kernel<<<dim3(4, 4, 7), 256, 0, stream>>>(Mtmp, final_w, flag, Dstack);
    bias1_kernel<<<256, 256, 0, stream>>>(s_l_w, s_a_w, s_v_w, out_b,
                                          s_l_b, s_a_b, s_v_b, flag, c0);
    bias2_kernel<<<256, 256, 0, stream>>>(c0, final_w, final_b, flag, d0);
    final_gemm_kernel<<<dim3(8, 96), 256, 0, stream>>>(O, Dstack, d0, flag, d_out);
}

// Round 10
// 365.716 us; speedup vs baseline: 1.1043x; 1.1043x over previous
//
#include <hip/hip_runtime.h>
#include <hip/hip_bf16.h>

#define E 256
#define H 8
#define HD 32
#define T 768
#define B 4
#define BH 32
// segments: L=[0,300), A=[300,550), V=[550,768)

__device__ __forceinline__ float b2f(__hip_bfloat16 x) { return __bfloat162float(x); }

// dtype-agnostic scalar load: f32 ? float : bf16
__device__ __forceinline__ float ldu(const void* p, size_t i, int f32) {
    if (f32) return ((const float*)p)[i];
    return b2f(((const __hip_bfloat16*)p)[i]);
}

// ---------------------------------------------------------------------------
// Kernel 0: input dtype detection (fp32 read as bf16 -> garbage exponents).
// ---------------------------------------------------------------------------
__global__ void detect_kernel(const unsigned short* __restrict__ q,
                              int* __restrict__ flag) {
    if (threadIdx.x == 0 && blockIdx.x == 0) {
        int f32 = 0;
        for (int i = 0; i < 256; ++i) {
            unsigned int bits = ((unsigned int)q[i]) << 16;
            float v = __uint_as_float(bits);
            if (!(v == v) || fabsf(v) > 1e4f) f32 = 1;
        }
        *flag = f32;
    }
}

// ---------------------------------------------------------------------------
// Kernel 1: QKV projection as a tiled GEMM. (proven round-4)
// ---------------------------------------------------------------------------
__global__ __launch_bounds__(256) void qkv_gemm_kernel(
    const void* query, const void* key, const void* value,
    const void* w, const void* bias, const int* __restrict__ flag,
    float* __restrict__ qws, float* __restrict__ kws, float* __restrict__ vws)
{
    int f32 = *flag;
    int bx = blockIdx.x;              // 0..11 col tiles
    int by = blockIdx.y;              // 0..47 row tiles
    int sec = bx >> 2;                // 0=q, 1=k, 2=v
    const void* X = (sec == 0) ? query : (sec == 1) ? key : value;
    int colbase = bx * 64;
    int rowbase = by * 64;
    int tid = threadIdx.x;
    int tx = tid & 15, ty = tid >> 4;
    __shared__ float As[64][33];
    __shared__ float Bs[32][65];
    float acc[4][4] = {};

    for (int kb = 0; kb < 8; ++kb) {
        __syncthreads();
        #pragma unroll
        for (int l = 0; l < 8; ++l) {
            int idx = l * 256 + tid;
            int r = idx >> 5, c = idx & 31;
            As[r][c] = ldu(X, (size_t)(rowbase + r) * 256 + kb * 32 + c, f32);
            int n = idx >> 5, kk = idx & 31;
            Bs[kk][n] = ldu(w, (size_t)(colbase + n) * 256 + kb * 32 + kk, f32);
        }
        __syncthreads();
        #pragma unroll 8
        for (int kk = 0; kk < 32; ++kk) {
            float av[4], bv[4];
            #pragma unroll
            for (int u = 0; u < 4; ++u) av[u] = As[ty * 4 + u][kk];
            #pragma unroll
            for (int v = 0; v < 4; ++v) bv[v] = Bs[kk][tx * 4 + v];
            #pragma unroll
            for (int u = 0; u < 4; ++u)
                #pragma unroll
                for (int v = 0; v < 4; ++v)
                    acc[u][v] += av[u] * bv[v];
        }
    }
    float* dst = (sec == 0) ? qws : (sec == 1) ? kws : vws;
    #pragma unroll
    for (int u = 0; u < 4; ++u)
        #pragma unroll
        for (int v = 0; v < 4; ++v) {
            int r = rowbase + ty * 4 + u;          // t*B + b
            int cg = colbase + tx * 4 + v;         // 0..767
            float val = acc[u][v] + ldu(bias, cg, f32);
            if (sec == 0) val *= 0.17677669529663687f;  // HD^-0.5
            int e_local = cg & 255;
            int h = e_local >> 5, hd = e_local & 31;
            int t = r >> 2, b = r & 3;
            dst[((size_t)((b * H + h) * T + t)) * HD + hd] = val;
        }
}

// ---------------------------------------------------------------------------
// Kernel 2: attention, round-10 layout rework. Grid (24,32), 32-row t-tiles.
// LDS-instr-throughput was the floor (r9 post-mortem): now k/q/e stored
// TRANSPOSED so Phase A reads b128(k)+b64(q) per kk and Phase B is a
// register-tiled GEMM: per ss, b128(e: 4 t-rows) x b128(v: 4 hd) -> 16 FMA.
// Phase B ss-range split per WAVE (wave-uniform segment bounds); partial
// pacc reduced once at the end via LDS aliased over dead staging buffers.
// ---------------------------------------------------------------------------
#define Q_OFF 0      // q_sT [32 hd][36]  (col = t-row)
#define K_OFF 1152   // k_sT [32 hd][68]  (col = s-col)
#define V_OFF 3328   // v_s  [64 s][36]   (col = hd)
#define E_OFF 5632   // e_sT [64 s][36]   (col = t-row)
#define S_OFF 7936   // S_s  [32 t][3]
#define R_OFF 1152   // red4 [4 wave][32 t][36] — epilogue only, aliases k/v/e

#define PV4(SEG)                                                            \
    {                                                                       \
        const float4 e4 = *(const float4*)&smem[E_OFF + ss * 36 + tq * 4];  \
        const float4 v4 = *(const float4*)&smem[V_OFF + ss * 36 + hq * 4];  \
        pacc[SEG][0][0] += e4.x * v4.x; pacc[SEG][0][1] += e4.x * v4.y;     \
        pacc[SEG][0][2] += e4.x * v4.z; pacc[SEG][0][3] += e4.x * v4.w;     \
        pacc[SEG][1][0] += e4.y * v4.x; pacc[SEG][1][1] += e4.y * v4.y;     \
        pacc[SEG][1][2] += e4.y * v4.z; pacc[SEG][1][3] += e4.y * v4.w;     \
        pacc[SEG][2][0] += e4.z * v4.x; pacc[SEG][2][1] += e4.z * v4.y;     \
        pacc[SEG][2][2] += e4.z * v4.z; pacc[SEG][2][3] += e4.z * v4.w;     \
        pacc[SEG][3][0] += e4.w * v4.x; pacc[SEG][3][1] += e4.w * v4.y;     \
        pacc[SEG][3][2] += e4.w * v4.z; pacc[SEG][3][3] += e4.w * v4.w;     \
    }

__global__ __launch_bounds__(256) void attn_tiled_kernel(
    const float* __restrict__ qws, const float* __restrict__ kws,
    const float* __restrict__ vws, float* __restrict__ O)
{
    int tile = blockIdx.x;       // 0..23
    int bh   = blockIdx.y;       // 0..31
    int t0 = tile * 32;
    int tid = threadIdx.x;
    int tx = tid & 15, ty = tid >> 4;        // Phase A layout
    int wv = tid >> 6;                       // wave id 0..3 (Phase B ss-quarter)
    int tq = tid & 7, hq = (tid >> 3) & 7;   // Phase B layout (t-quad, hd-quad)

    __shared__ __align__(16) float smem[8032];

    // Stage q transposed: q_sT[hd][t]
    const float* qbase = qws + ((size_t)bh * T + t0) * HD;
    #pragma unroll
    for (int l = 0; l < 4; ++l) {
        int idx = l * 256 + tid;             // t*32 + hd
        smem[Q_OFF + (idx & 31) * 36 + (idx >> 5)] = qbase[idx];
    }

    float pacc[3][4][4] = {};   // [seg][t-row in quad][hd in quad], ss-quarter partial
    float ssum[3][2] = {};      // Phase A layout: [seg][t-row pair]

    const float* kbase = kws + (size_t)bh * T * HD;
    const float* vbase = vws + (size_t)bh * T * HD;

    for (int ch = 0; ch < 12; ++ch) {
        int base = ch * 64;
        __syncthreads();
        // Stage: k transposed (scalar LDS writes from float4 global),
        //        v row-major (float4 all the way).
        const float4* kg = (const float4*)(kbase + (size_t)base * HD);
        const float4* vg = (const float4*)(vbase + (size_t)base * HD);
        #pragma unroll
        for (int l2 = 0; l2 < 2; ++l2) {
            int idx4 = l2 * 256 + tid;       // s*8 + h4
            int s = idx4 >> 3, h4 = (idx4 & 7) * 4;
            float4 kq = kg[idx4];
            smem[K_OFF + (h4 + 0) * 68 + s] = kq.x;
            smem[K_OFF + (h4 + 1) * 68 + s] = kq.y;
            smem[K_OFF + (h4 + 2) * 68 + s] = kq.z;
            smem[K_OFF + (h4 + 3) * 68 + s] = kq.w;
            *(float4*)&smem[V_OFF + s * 36 + h4] = vg[idx4];
        }
        __syncthreads();

        // Phase A: 2x4 score tile; per kk: 1 b64 (q pair) + 1 b128 (k quad).
        float sc[2][4] = {};
        #pragma unroll 8
        for (int kk = 0; kk < 32; ++kk) {
            const float2 qv = *(const float2*)&smem[Q_OFF + kk * 36 + ty * 2];
            const float4 kv = *(const float4*)&smem[K_OFF + kk * 68 + tx * 4];
            sc[0][0] += qv.x * kv.x; sc[0][1] += qv.x * kv.y;
            sc[0][2] += qv.x * kv.z; sc[0][3] += qv.x * kv.w;
            sc[1][0] += qv.y * kv.x; sc[1][1] += qv.y * kv.y;
            sc[1][2] += qv.y * kv.z; sc[1][3] += qv.y * kv.w;
        }
        #pragma unroll
        for (int u = 0; u < 2; ++u)
            #pragma unroll
            for (int vv = 0; vv < 4; ++vv) {
                float e = __expf(sc[u][vv]);
                int sg = base + tx * 4 + vv;
                if (sg < 300) ssum[0][u] += e;
                else if (sg < 550) ssum[1][u] += e;
                else ssum[2][u] += e;
                smem[E_OFF + (tx * 4 + vv) * 36 + ty * 2 + u] = e;  // e_sT[s][t]
            }
        __syncthreads();

        // Phase B: wave wv covers ss in [wv*16, wv*16+16); uniform seg bounds.
        int e0 = min(max(300 - base, 0), 64);
        int e1 = min(max(550 - base, 0), 64);
        int lo = wv * 16, hi = lo + 16;
        for (int ss = lo, z = min(hi, e0); ss < z; ++ss) PV4(0)
        for (int ss = max(lo, e0), z = min(hi, e1); ss < z; ++ss) PV4(1)
        for (int ss = max(lo, e1); ss < hi; ++ss) PV4(2)
    }

    // Reduce ssum across tx (Phase A layout) -> S_s[t][seg].
    #pragma unroll
    for (int sg = 0; sg < 3; ++sg)
        #pragma unroll
        for (int u = 0; u < 2; ++u) {
            float v = ssum[sg][u];
            v += __shfl_down(v, 8, 16);
            v += __shfl_down(v, 4, 16);
            v += __shfl_down(v, 2, 16);
            v += __shfl_down(v, 1, 16);
            if (tx == 0) smem[S_OFF + (ty * 2 + u) * 3 + sg] = v;
        }
    __syncthreads();   // all Phase B done -> staging region dead; S_s visible

    // Cross-wave pacc reduction via red4 (aliased), one seg at a time.
    int tt = tid >> 3, q4 = tid & 7;       // epilogue layout: t-row, hd-quad
    float Pv[3][4];
    #pragma unroll
    for (int sg = 0; sg < 3; ++sg) {
        #pragma unroll
        for (int u = 0; u < 4; ++u)
            #pragma unroll
            for (int j = 0; j < 4; ++j)
                smem[R_OFF + wv * 1152 + (tq * 4 + u) * 36 + hq * 4 + j] =
                    pacc[sg][u][j];
        __syncthreads();
        float s0 = 0.f, s1 = 0.f, s2 = 0.f, s3 = 0.f;
        #pragma unroll
        for (int w = 0; w < 4; ++w) {
            const float4 r = *(const float4*)&smem[R_OFF + w * 1152 + tt * 36 + q4 * 4];
            s0 += r.x; s1 += r.y; s2 += r.z; s3 += r.w;
        }
        Pv[sg][0] = s0; Pv[sg][1] = s1; Pv[sg][2] = s2; Pv[sg][3] = s3;
        __syncthreads();
    }

    // Epilogue: 7 branch outputs, float4 per branch.
    int t_glob = t0 + tt;
    int g = (t_glob < 300) ? 0 : (t_glob < 550 ? 1 : 2);
    float S0 = smem[S_OFF + tt * 3 + 0];
    float S1 = smem[S_OFF + tt * 3 + 1];
    float S2 = smem[S_OFF + tt * 3 + 2];
    int b = bh >> 3, h = bh & 7;
    float* orow = O + (size_t)(t_glob * B + b) * 1792 + h * 32 + q4 * 4;
    const int masks[7] = {7, 3, 5, 6, 1, 2, 4};  // LAV,LA,LV,AV,L,A,V
    #pragma unroll
    for (int i = 0; i < 7; ++i) {
        int m = masks[i];
        float n0 = 0.f, n1 = 0.f, n2 = 0.f, n3 = 0.f, den = 0.f;
        if (m & 1) { n0 += Pv[0][0]; n1 += Pv[0][1]; n2 += Pv[0][2]; n3 += Pv[0][3]; den += S0; }
        if (m & 2) { n0 += Pv[1][0]; n1 += Pv[1][1]; n2 += Pv[1][2]; n3 += Pv[1][3]; den += S1; }
        if (m & 4) { n0 += Pv[2][0]; n1 += Pv[2][1]; n2 += Pv[2][2]; n3 += Pv[2][3]; den += S2; }
        float r = 1.f / den;
        int live = (m >> g) & 1;
        float4 o4;
        o4.x = live ? n0 * r : 0.f;
        o4.y = live ? n1 * r : 0.f;
        o4.z = live ? n2 * r : 0.f;
        o4.w = live ? n3 * r : 0.f;
        *(float4*)&orow[i * 256] = o4;
    }
}

// ---------------------------------------------------------------------------
// Weight combination: D_i = (final_w @ G_i @ out_w[i])^T stacked as (1792,256).
// ---------------------------------------------------------------------------
__device__ __forceinline__ float gsum_load(int i, int r2, int r,
                                           const void* sl, const void* sa,
                                           const void* sv, int f32)
{
    size_t base = (size_t)r2 * 1024;
    switch (i) {
        case 0: return ldu(sl, base + r, f32) + ldu(sa, base + r, f32) + ldu(sv, base + r, f32);
        case 1: return ldu(sl, base + 256 + r, f32) + ldu(sa, base + 256 + r, f32);
        case 2: return ldu(sl, base + 512 + r, f32) + ldu(sv, base + 256 + r, f32);
        case 3: return ldu(sa, base + 512 + r, f32) + ldu(sv, base + 512 + r, f32);
        case 4: return ldu(sl, base + 768 + r, f32);
        case 5: return ldu(sa, base + 768 + r, f32);
        default: return ldu(sv, base + 768 + r, f32);
    }
}

// Mtmp_i = G_i @ out_w[i]    (proven round-2)
__global__ __launch_bounds__(256) void wcomb1_kernel(
    const void* sl, const void* sa, const void* sv, const void* outw,
    const int* __restrict__ flag, float* __restrict__ Mtmp)
{
    int f32 = *flag;
    int bid = blockIdx.x;
    int i = bid >> 8, r2 = bid & 255;
    int c = threadIdx.x;
    __shared__ float g[256];
    g[c] = gsum_load(i, r2, c, sl, sa, sv, f32);
    __syncthreads();
    float acc = 0.f;
    for (int r = 0; r < 256; ++r)
        acc += g[r] * ldu(outw, (size_t)i * 65536 + r * 256 + c, f32);
    Mtmp[(size_t)i * 65536 + r2 * 256 + c] = acc;
}

// Dstack_i = Mtmp_i^T @ final_w^T as tiled GEMM (proven round-7).
__global__ __launch_bounds__(256) void wcomb2_gemm_kernel(
    const float* __restrict__ Mtmp, const void* finalw,
    const int* __restrict__ flag, float* __restrict__ Dstack)
{
    int f32 = *flag;
    int bx = blockIdx.x;   // col tile 0..3 (e)
    int by = blockIdx.y;   // row tile 0..3 (c)
    int i  = blockIdx.z;   // branch 0..6
    int tid = threadIdx.x;
    int tx = tid & 15, ty = tid >> 4;
    int colbase = bx * 64, rowbase = by * 64;
    __shared__ float As[64][33];   // Mtmp^T [c][j]
    __shared__ float Bs[32][65];   // finalw^T [j][e]
    float acc[4][4] = {};

    for (int kb = 0; kb < 8; ++kb) {
        __syncthreads();
        #pragma unroll
        for (int l = 0; l < 8; ++l) {
            int idx = l * 256 + tid;
            int r = idx & 63, kk = idx >> 6;      // r contiguous -> coalesced
            As[r][kk] = Mtmp[(size_t)i * 65536 + (kb * 32 + kk) * 256 + rowbase + r];
            int n = idx >> 5, k2 = idx & 31;      // k2 contiguous -> coalesced
            Bs[k2][n] = ldu(finalw, (size_t)(colbase + n) * 256 + kb * 32 + k2, f32);
        }
        __syncthreads();
        #pragma unroll 8
        for (int kk = 0; kk < 32; ++kk) {
            float av[4], bv[4];
            #pragma unroll
            for (int u = 0; u < 4; ++u) av[u] = As[ty * 4 + u][kk];
            #pragma unroll
            for (int v = 0; v < 4; ++v) bv[v] = Bs[kk][tx * 4 + v];
            #pragma unroll
            for (int u = 0; u < 4; ++u)
                #pragma unroll
                for (int v = 0; v < 4; ++v)
                    acc[u][v] += av[u] * bv[v];
        }
    }
    #pragma unroll
    for (int u = 0; u < 4; ++u)
        #pragma unroll
        for (int v = 0; v < 4; ++v) {
            int c = rowbase + ty * 4 + u, e = colbase + tx * 4 + v;
            Dstack[(size_t)(i * 256 + c) * 256 + e] = acc[u][v];
        }
}

// ---------------------------------------------------------------------------
// Bias path (proven round-5). c0 ALIASES Mtmp (dead after wcomb2).
// ws footprint unchanged from proven layout — do NOT grow it.
// ---------------------------------------------------------------------------
__global__ __launch_bounds__(256) void bias1_kernel(
    const void* sl, const void* sa, const void* sv, const void* outb,
    const void* slb, const void* sab, const void* svb,
    const int* __restrict__ flag, float* __restrict__ c0)
{
    int f32 = *flag;
    int r2 = blockIdx.x, m = threadIdx.x;
    __shared__ float red[256];
    float acc = 0.f;
    #pragma unroll
    for (int i = 0; i < 7; ++i)
        acc += ldu(outb, i * 256 + m, f32) * gsum_load(i, r2, m, sl, sa, sv, f32);
    red[m] = acc;
    __syncthreads();
    for (int s = 128; s > 0; s >>= 1) {
        if (m < s) red[m] += red[m + s];
        __syncthreads();
    }
    if (m == 0)
        c0[r2] = red[0] + ldu(slb, r2, f32) + ldu(sab, r2, f32) + ldu(svb, r2, f32);
}

__global__ __launch_bounds__(256) void bias2_kernel(
    const float* __restrict__ c0, const void* finalw, const void* finalb,
    const int* __restrict__ flag, float* __restrict__ d0)
{
    int f32 = *flag;
    int e = blockIdx.x, r = threadIdx.x;
    __shared__ float red[256];
    red[r] = c0[r] * ldu(finalw, (size_t)e * 256 + r, f32);
    __syncthreads();
    for (int s = 128; s > 0; s >>= 1) {
        if (r < s) red[r] += red[r + s];
        __syncthreads();
    }
    if (r == 0)
        d0[e] = red[0] + ldu(finalb, e, f32);
}

// ---------------------------------------------------------------------------
// Kernel 4: result = O (3072x1792) @ Dstack (1792x256) + d0 (proven round-8:
// 32x32 tiles, grid (8,96) = 768 blocks).
// ---------------------------------------------------------------------------
__global__ __launch_bounds__(256) void final_gemm_kernel(
    const float* __restrict__ O, const float* __restrict__ Dstack,
    const float* __restrict__ d0, const int* __restrict__ flag,
    void* __restrict__ outv)
{
    int f32 = *flag;
    int bx = blockIdx.x;   // col tile 0..7 (32 cols)
    int by = blockIdx.y;   // row tile 0..95 (32 rows = 8 t values)
    int tid = threadIdx.x;
    int tx = tid & 15, ty = tid >> 4;
    __shared__ float As[32][33];
    __shared__ float Bs[32][33];
    float acc[2][2] = {};

    int t0 = by * 8, t1 = t0 + 7;
    int g0 = (t0 < 300) ? 0 : (t0 < 550 ? 1 : 2);
    int g1 = (t1 < 300) ? 0 : (t1 < 550 ? 1 : 2);
    int activeset = (1 << g0) | (1 << g1);
    const int masks[7] = {7, 3, 5, 6, 1, 2, 4};
    int rowbase = by * 32, colbase = bx * 32;

    for (int i = 0; i < 7; ++i) {
        if (!(masks[i] & activeset)) continue;   // whole O block is zero
        for (int kb = 0; kb < 8; ++kb) {
            int cb = i * 256 + kb * 32;
            __syncthreads();
            #pragma unroll
            for (int l = 0; l < 4; ++l) {
                int idx = l * 256 + tid;
                int r = idx >> 5, c = idx & 31;
                As[r][c] = O[(size_t)(rowbase + r) * 1792 + cb + c];
                Bs[r][c] = Dstack[(size_t)(cb + r) * 256 + colbase + c];
            }
            __syncthreads();
            #pragma unroll 8
            for (int kk = 0; kk < 32; ++kk) {
                float a0 = As[ty * 2][kk], a1 = As[ty * 2 + 1][kk];
                float b0 = Bs[kk][tx * 2], b1 = Bs[kk][tx * 2 + 1];
                acc[0][0] += a0 * b0; acc[0][1] += a0 * b1;
                acc[1][0] += a1 * b0; acc[1][1] += a1 * b1;
            }
        }
    }
    #pragma unroll
    for (int u = 0; u < 2; ++u)
        #pragma unroll
        for (int v = 0; v < 2; ++v) {
            int r = rowbase + ty * 2 + u, c = colbase + tx * 2 + v;
            float val = acc[u][v] + d0[c];
            if (f32) ((float*)outv)[(size_t)r * 256 + c] = val;
            else ((__hip_bfloat16*)outv)[(size_t)r * 256 + c] = __float2bfloat16(val);
        }
}

// ---------------------------------------------------------------------------
extern "C" void kernel_launch(void* const* d_in, const int* in_sizes, int n_in,
                              void* d_out, int out_size, void* d_ws, size_t ws_size,
                              hipStream_t stream) {
    const void* query     = d_in[0];
    const void* key       = d_in[1];
    const void* value     = d_in[2];
    const void* in_proj_w = d_in[3];
    const void* in_proj_b = d_in[4];
    const void* out_w     = d_in[5];
    const void* out_b     = d_in[6];
    const void* s_l_w     = d_in[7];
    const void* s_l_b     = d_in[8];
    const void* s_a_w     = d_in[9];
    const void* s_a_b     = d_in[10];
    const void* s_v_w     = d_in[11];
    const void* s_v_b     = d_in[12];
    const void* final_w   = d_in[13];
    const void* final_b   = d_in[14];

    float* ws     = (float*)d_ws;
    float* qws    = ws;                 //   786432 f
    float* kws    = ws + 786432;        //   786432 f
    float* vws    = ws + 1572864;       //   786432 f
    float* O      = ws + 2359296;       //  5505024 f (3072 x 1792)
    float* Mtmp   = ws + 7864320;       //   458752 f
    float* Dstack = ws + 8323072;       //   458752 f (1792 x 256)
    float* d0     = ws + 8781824;       //      256 f
    int*   flag   = (int*)(ws + 8782080);  // 1 int — proven footprint HIGH-WATER
    float* c0     = Mtmp;               // ALIAS: Mtmp dead after wcomb2

    detect_kernel<<<1, 64, 0, stream>>>((const unsigned short*)query, flag);
    qkv_gemm_kernel<<<dim3(12, 48), 256, 0, stream>>>(query, key, value,
                                                      in_proj_w, in_proj_b, flag,
                                                      qws, kws, vws);
    wcomb1_kernel<<<7 * 256, 256, 0, stream>>>(s_l_w, s_a_w, s_v_w, out_w, flag, Mtmp);
    attn_tiled_kernel<<<dim3(24, 32), 256, 0, stream>>>(qws, kws, vws, O);
    wcomb2_gemm_kernel<<<dim3(4, 4, 7), 256, 0, stream>>>(Mtmp, final_w, flag, Dstack);
    bias1_kernel<<<256, 256, 0, stream>>>(s_l_w, s_a_w, s_v_w, out_b,
                                          s_l_b, s_a_b, s_v_b, flag, c0);
    bias2_kernel<<<256, 256, 0, stream>>>(c0, final_w, final_b, flag, d0);
    final_gemm_kernel<<<dim3(8, 96), 256, 0, stream>>>(O, Dstack, d0, flag, d_out);
}

// Round 11
// 333.199 us; speedup vs baseline: 1.2121x; 1.0976x over previous
//
#include <hip/hip_runtime.h>
#include <hip/hip_bf16.h>

#define E 256
#define H 8
#define HD 32
#define T 768
#define B 4
#define BH 32
// segments: L=[0,300), A=[300,550), V=[550,768)

typedef __attribute__((ext_vector_type(8))) short bf16x8;
typedef __attribute__((ext_vector_type(4))) float f32x4;

__device__ __forceinline__ float b2f(__hip_bfloat16 x) { return __bfloat162float(x); }

__device__ __forceinline__ unsigned short f2bf_u(float x) {
    __hip_bfloat16 h = __float2bfloat16(x);
    return *(unsigned short*)&h;
}
__device__ __forceinline__ float bfu2f(unsigned short u) {
    return __uint_as_float(((unsigned int)u) << 16);
}

// dtype-agnostic scalar load: f32 ? float : bf16
__device__ __forceinline__ float ldu(const void* p, size_t i, int f32) {
    if (f32) return ((const float*)p)[i];
    return b2f(((const __hip_bfloat16*)p)[i]);
}

// ---------------------------------------------------------------------------
// Kernel 0: input dtype detection (fp32 read as bf16 -> garbage exponents).
// ---------------------------------------------------------------------------
__global__ void detect_kernel(const unsigned short* __restrict__ q,
                              int* __restrict__ flag) {
    if (threadIdx.x == 0 && blockIdx.x == 0) {
        int f32 = 0;
        for (int i = 0; i < 256; ++i) {
            unsigned int bits = ((unsigned int)q[i]) << 16;
            float v = __uint_as_float(bits);
            if (!(v == v) || fabsf(v) > 1e4f) f32 = 1;
        }
        *flag = f32;
    }
}

// ---------------------------------------------------------------------------
// Kernel 1: QKV projection as a tiled GEMM. (proven round-4)
// ---------------------------------------------------------------------------
__global__ __launch_bounds__(256) void qkv_gemm_kernel(
    const void* query, const void* key, const void* value,
    const void* w, const void* bias, const int* __restrict__ flag,
    float* __restrict__ qws, float* __restrict__ kws, float* __restrict__ vws)
{
    int f32 = *flag;
    int bx = blockIdx.x;              // 0..11 col tiles
    int by = blockIdx.y;              // 0..47 row tiles
    int sec = bx >> 2;                // 0=q, 1=k, 2=v
    const void* X = (sec == 0) ? query : (sec == 1) ? key : value;
    int colbase = bx * 64;
    int rowbase = by * 64;
    int tid = threadIdx.x;
    int tx = tid & 15, ty = tid >> 4;
    __shared__ float As[64][33];
    __shared__ float Bs[32][65];
    float acc[4][4] = {};

    for (int kb = 0; kb < 8; ++kb) {
        __syncthreads();
        #pragma unroll
        for (int l = 0; l < 8; ++l) {
            int idx = l * 256 + tid;
            int r = idx >> 5, c = idx & 31;
            As[r][c] = ldu(X, (size_t)(rowbase + r) * 256 + kb * 32 + c, f32);
            int n = idx >> 5, kk = idx & 31;
            Bs[kk][n] = ldu(w, (size_t)(colbase + n) * 256 + kb * 32 + kk, f32);
        }
        __syncthreads();
        #pragma unroll 8
        for (int kk = 0; kk < 32; ++kk) {
            float av[4], bv[4];
            #pragma unroll
            for (int u = 0; u < 4; ++u) av[u] = As[ty * 4 + u][kk];
            #pragma unroll
            for (int v = 0; v < 4; ++v) bv[v] = Bs[kk][tx * 4 + v];
            #pragma unroll
            for (int u = 0; u < 4; ++u)
                #pragma unroll
                for (int v = 0; v < 4; ++v)
                    acc[u][v] += av[u] * bv[v];
        }
    }
    float* dst = (sec == 0) ? qws : (sec == 1) ? kws : vws;
    #pragma unroll
    for (int u = 0; u < 4; ++u)
        #pragma unroll
        for (int v = 0; v < 4; ++v) {
            int r = rowbase + ty * 4 + u;          // t*B + b
            int cg = colbase + tx * 4 + v;         // 0..767
            float val = acc[u][v] + ldu(bias, cg, f32);
            if (sec == 0) val *= 0.17677669529663687f;  // HD^-0.5
            int e_local = cg & 255;
            int h = e_local >> 5, hd = e_local & 31;
            int t = r >> 2, b = r & 3;
            dst[((size_t)((b * H + h) * T + t)) * HD + hd] = val;
        }
}

// ---------------------------------------------------------------------------
// Kernel 2: attention (proven round-10 transposed-LDS version), epilogue now
// emits O as bf16 HI+LO planes (hi = bf16(x), lo = bf16(x - hi)) for the
// MFMA final GEMM. Same ws region, split 11MB+11MB.
// ---------------------------------------------------------------------------
#define Q_OFF 0      // q_sT [32 hd][36]  (col = t-row)
#define K_OFF 1152   // k_sT [32 hd][68]  (col = s-col)
#define V_OFF 3328   // v_s  [64 s][36]   (col = hd)
#define E_OFF 5632   // e_sT [64 s][36]   (col = t-row)
#define S_OFF 7936   // S_s  [32 t][3]
#define R_OFF 1152   // red4 [4 wave][32 t][36] — epilogue only, aliases k/v/e

#define PV4(SEG)                                                            \
    {                                                                       \
        const float4 e4 = *(const float4*)&smem[E_OFF + ss * 36 + tq * 4];  \
        const float4 v4 = *(const float4*)&smem[V_OFF + ss * 36 + hq * 4];  \
        pacc[SEG][0][0] += e4.x * v4.x; pacc[SEG][0][1] += e4.x * v4.y;     \
        pacc[SEG][0][2] += e4.x * v4.z; pacc[SEG][0][3] += e4.x * v4.w;     \
        pacc[SEG][1][0] += e4.y * v4.x; pacc[SEG][1][1] += e4.y * v4.y;     \
        pacc[SEG][1][2] += e4.y * v4.z; pacc[SEG][1][3] += e4.y * v4.w;     \
        pacc[SEG][2][0] += e4.z * v4.x; pacc[SEG][2][1] += e4.z * v4.y;     \
        pacc[SEG][2][2] += e4.z * v4.z; pacc[SEG][2][3] += e4.z * v4.w;     \
        pacc[SEG][3][0] += e4.w * v4.x; pacc[SEG][3][1] += e4.w * v4.y;     \
        pacc[SEG][3][2] += e4.w * v4.z; pacc[SEG][3][3] += e4.w * v4.w;     \
    }

__global__ __launch_bounds__(256) void attn_tiled_kernel(
    const float* __restrict__ qws, const float* __restrict__ kws,
    const float* __restrict__ vws,
    unsigned short* __restrict__ Ohi, unsigned short* __restrict__ Olo)
{
    int tile = blockIdx.x;       // 0..23
    int bh   = blockIdx.y;       // 0..31
    int t0 = tile * 32;
    int tid = threadIdx.x;
    int tx = tid & 15, ty = tid >> 4;        // Phase A layout
    int wv = tid >> 6;                       // wave id 0..3 (Phase B ss-quarter)
    int tq = tid & 7, hq = (tid >> 3) & 7;   // Phase B layout (t-quad, hd-quad)

    __shared__ __align__(16) float smem[8032];

    // Stage q transposed: q_sT[hd][t]
    const float* qbase = qws + ((size_t)bh * T + t0) * HD;
    #pragma unroll
    for (int l = 0; l < 4; ++l) {
        int idx = l * 256 + tid;             // t*32 + hd
        smem[Q_OFF + (idx & 31) * 36 + (idx >> 5)] = qbase[idx];
    }

    float pacc[3][4][4] = {};   // [seg][t-row in quad][hd in quad], ss-quarter partial
    float ssum[3][2] = {};      // Phase A layout: [seg][t-row pair]

    const float* kbase = kws + (size_t)bh * T * HD;
    const float* vbase = vws + (size_t)bh * T * HD;

    for (int ch = 0; ch < 12; ++ch) {
        int base = ch * 64;
        __syncthreads();
        const float4* kg = (const float4*)(kbase + (size_t)base * HD);
        const float4* vg = (const float4*)(vbase + (size_t)base * HD);
        #pragma unroll
        for (int l2 = 0; l2 < 2; ++l2) {
            int idx4 = l2 * 256 + tid;       // s*8 + h4
            int s = idx4 >> 3, h4 = (idx4 & 7) * 4;
            float4 kq = kg[idx4];
            smem[K_OFF + (h4 + 0) * 68 + s] = kq.x;
            smem[K_OFF + (h4 + 1) * 68 + s] = kq.y;
            smem[K_OFF + (h4 + 2) * 68 + s] = kq.z;
            smem[K_OFF + (h4 + 3) * 68 + s] = kq.w;
            *(float4*)&smem[V_OFF + s * 36 + h4] = vg[idx4];
        }
        __syncthreads();

        // Phase A: 2x4 score tile; per kk: 1 b64 (q pair) + 1 b128 (k quad).
        float sc[2][4] = {};
        #pragma unroll 8
        for (int kk = 0; kk < 32; ++kk) {
            const float2 qv = *(const float2*)&smem[Q_OFF + kk * 36 + ty * 2];
            const float4 kv = *(const float4*)&smem[K_OFF + kk * 68 + tx * 4];
            sc[0][0] += qv.x * kv.x; sc[0][1] += qv.x * kv.y;
            sc[0][2] += qv.x * kv.z; sc[0][3] += qv.x * kv.w;
            sc[1][0] += qv.y * kv.x; sc[1][1] += qv.y * kv.y;
            sc[1][2] += qv.y * kv.z; sc[1][3] += qv.y * kv.w;
        }
        #pragma unroll
        for (int u = 0; u < 2; ++u)
            #pragma unroll
            for (int vv = 0; vv < 4; ++vv) {
                float e = __expf(sc[u][vv]);
                int sg = base + tx * 4 + vv;
                if (sg < 300) ssum[0][u] += e;
                else if (sg < 550) ssum[1][u] += e;
                else ssum[2][u] += e;
                smem[E_OFF + (tx * 4 + vv) * 36 + ty * 2 + u] = e;  // e_sT[s][t]
            }
        __syncthreads();

        // Phase B: wave wv covers ss in [wv*16, wv*16+16); uniform seg bounds.
        int e0 = min(max(300 - base, 0), 64);
        int e1 = min(max(550 - base, 0), 64);
        int lo = wv * 16, hi = lo + 16;
        for (int ss = lo, z = min(hi, e0); ss < z; ++ss) PV4(0)
        for (int ss = max(lo, e0), z = min(hi, e1); ss < z; ++ss) PV4(1)
        for (int ss = max(lo, e1); ss < hi; ++ss) PV4(2)
    }

    // Reduce ssum across tx (Phase A layout) -> S_s[t][seg].
    #pragma unroll
    for (int sg = 0; sg < 3; ++sg)
        #pragma unroll
        for (int u = 0; u < 2; ++u) {
            float v = ssum[sg][u];
            v += __shfl_down(v, 8, 16);
            v += __shfl_down(v, 4, 16);
            v += __shfl_down(v, 2, 16);
            v += __shfl_down(v, 1, 16);
            if (tx == 0) smem[S_OFF + (ty * 2 + u) * 3 + sg] = v;
        }
    __syncthreads();   // all Phase B done -> staging region dead; S_s visible

    // Cross-wave pacc reduction via red4 (aliased), one seg at a time.
    int tt = tid >> 3, q4 = tid & 7;       // epilogue layout: t-row, hd-quad
    float Pv[3][4];
    #pragma unroll
    for (int sg = 0; sg < 3; ++sg) {
        #pragma unroll
        for (int u = 0; u < 4; ++u)
            #pragma unroll
            for (int j = 0; j < 4; ++j)
                smem[R_OFF + wv * 1152 + (tq * 4 + u) * 36 + hq * 4 + j] =
                    pacc[sg][u][j];
        __syncthreads();
        float s0 = 0.f, s1 = 0.f, s2 = 0.f, s3 = 0.f;
        #pragma unroll
        for (int w = 0; w < 4; ++w) {
            const float4 r = *(const float4*)&smem[R_OFF + w * 1152 + tt * 36 + q4 * 4];
            s0 += r.x; s1 += r.y; s2 += r.z; s3 += r.w;
        }
        Pv[sg][0] = s0; Pv[sg][1] = s1; Pv[sg][2] = s2; Pv[sg][3] = s3;
        __syncthreads();
    }

    // Epilogue: 7 branch outputs, bf16 hi+lo (8B stores each).
    int t_glob = t0 + tt;
    int g = (t_glob < 300) ? 0 : (t_glob < 550 ? 1 : 2);
    float S0 = smem[S_OFF + tt * 3 + 0];
    float S1 = smem[S_OFF + tt * 3 + 1];
    float S2 = smem[S_OFF + tt * 3 + 2];
    int b = bh >> 3, h = bh & 7;
    size_t obase = (size_t)(t_glob * B + b) * 1792 + h * 32 + q4 * 4;
    const int masks[7] = {7, 3, 5, 6, 1, 2, 4};  // LAV,LA,LV,AV,L,A,V
    #pragma unroll
    for (int i = 0; i < 7; ++i) {
        int m = masks[i];
        float n0 = 0.f, n1 = 0.f, n2 = 0.f, n3 = 0.f, den = 0.f;
        if (m & 1) { n0 += Pv[0][0]; n1 += Pv[0][1]; n2 += Pv[0][2]; n3 += Pv[0][3]; den += S0; }
        if (m & 2) { n0 += Pv[1][0]; n1 += Pv[1][1]; n2 += Pv[1][2]; n3 += Pv[1][3]; den += S1; }
        if (m & 4) { n0 += Pv[2][0]; n1 += Pv[2][1]; n2 += Pv[2][2]; n3 += Pv[2][3]; den += S2; }
        float r = 1.f / den;
        int live = (m >> g) & 1;
        float o[4];
        o[0] = live ? n0 * r : 0.f;
        o[1] = live ? n1 * r : 0.f;
        o[2] = live ? n2 * r : 0.f;
        o[3] = live ? n3 * r : 0.f;
        ushort4 hi4, lo4;
        unsigned short* hp = (unsigned short*)&hi4;
        unsigned short* lp = (unsigned short*)&lo4;
        #pragma unroll
        for (int j = 0; j < 4; ++j) {
            unsigned short hu = f2bf_u(o[j]);
            hp[j] = hu;
            lp[j] = f2bf_u(o[j] - bfu2f(hu));
        }
        *(ushort4*)&Ohi[obase + (size_t)i * 256] = hi4;
        *(ushort4*)&Olo[obase + (size_t)i * 256] = lo4;
    }
}

// ---------------------------------------------------------------------------
// Weight combination: D_i = (final_w @ G_i @ out_w[i])^T stacked as (1792,256).
// ---------------------------------------------------------------------------
__device__ __forceinline__ float gsum_load(int i, int r2, int r,
                                           const void* sl, const void* sa,
                                           const void* sv, int f32)
{
    size_t base = (size_t)r2 * 1024;
    switch (i) {
        case 0: return ldu(sl, base + r, f32) + ldu(sa, base + r, f32) + ldu(sv, base + r, f32);
        case 1: return ldu(sl, base + 256 + r, f32) + ldu(sa, base + 256 + r, f32);
        case 2: return ldu(sl, base + 512 + r, f32) + ldu(sv, base + 256 + r, f32);
        case 3: return ldu(sa, base + 512 + r, f32) + ldu(sv, base + 512 + r, f32);
        case 4: return ldu(sl, base + 768 + r, f32);
        case 5: return ldu(sa, base + 768 + r, f32);
        default: return ldu(sv, base + 768 + r, f32);
    }
}

// Mtmp_i = G_i @ out_w[i]    (proven round-2)
__global__ __launch_bounds__(256) void wcomb1_kernel(
    const void* sl, const void* sa, const void* sv, const void* outw,
    const int* __restrict__ flag, float* __restrict__ Mtmp)
{
    int f32 = *flag;
    int bid = blockIdx.x;
    int i = bid >> 8, r2 = bid & 255;
    int c = threadIdx.x;
    __shared__ float g[256];
    g[c] = gsum_load(i, r2, c, sl, sa, sv, f32);
    __syncthreads();
    float acc = 0.f;
    for (int r = 0; r < 256; ++r)
        acc += g[r] * ldu(outw, (size_t)i * 65536 + r * 256 + c, f32);
    Mtmp[(size_t)i * 65536 + r2 * 256 + c] = acc;
}

// Dstack as TRANSPOSED bf16 hi+lo planes: DT[e][i*256+c], e in [0,256).
// (proven round-7 GEMM skeleton; only the store changed.)
__global__ __launch_bounds__(256) void wcomb2_gemm_kernel(
    const float* __restrict__ Mtmp, const void* finalw,
    const int* __restrict__ flag,
    unsigned short* __restrict__ DThi, unsigned short* __restrict__ DTlo)
{
    int f32 = *flag;
    int bx = blockIdx.x;   // col tile 0..3 (e)
    int by = blockIdx.y;   // row tile 0..3 (c)
    int i  = blockIdx.z;   // branch 0..6
    int tid = threadIdx.x;
    int tx = tid & 15, ty = tid >> 4;
    int colbase = bx * 64, rowbase = by * 64;
    __shared__ float As[64][33];   // Mtmp^T [c][j]
    __shared__ float Bs[32][65];   // finalw^T [j][e]
    float acc[4][4] = {};

    for (int kb = 0; kb < 8; ++kb) {
        __syncthreads();
        #pragma unroll
        for (int l = 0; l < 8; ++l) {
            int idx = l * 256 + tid;
            int r = idx & 63, kk = idx >> 6;      // r contiguous -> coalesced
            As[r][kk] = Mtmp[(size_t)i * 65536 + (kb * 32 + kk) * 256 + rowbase + r];
            int n = idx >> 5, k2 = idx & 31;      // k2 contiguous -> coalesced
            Bs[k2][n] = ldu(finalw, (size_t)(colbase + n) * 256 + kb * 32 + k2, f32);
        }
        __syncthreads();
        #pragma unroll 8
        for (int kk = 0; kk < 32; ++kk) {
            float av[4], bv[4];
            #pragma unroll
            for (int u = 0; u < 4; ++u) av[u] = As[ty * 4 + u][kk];
            #pragma unroll
            for (int v = 0; v < 4; ++v) bv[v] = Bs[kk][tx * 4 + v];
            #pragma unroll
            for (int u = 0; u < 4; ++u)
                #pragma unroll
                for (int v = 0; v < 4; ++v)
                    acc[u][v] += av[u] * bv[v];
        }
    }
    #pragma unroll
    for (int u = 0; u < 4; ++u)
        #pragma unroll
        for (int v = 0; v < 4; ++v) {
            int c = rowbase + ty * 4 + u, e = colbase + tx * 4 + v;
            float a = acc[u][v];
            unsigned short hu = f2bf_u(a);
            DThi[(size_t)e * 1792 + i * 256 + c] = hu;
            DTlo[(size_t)e * 1792 + i * 256 + c] = f2bf_u(a - bfu2f(hu));
        }
}

// ---------------------------------------------------------------------------
// Bias path (proven round-5). c0 ALIASES Mtmp (dead after wcomb2).
// ws footprint unchanged from proven layout — do NOT grow it.
// ---------------------------------------------------------------------------
__global__ __launch_bounds__(256) void bias1_kernel(
    const void* sl, const void* sa, const void* sv, const void* outb,
    const void* slb, const void* sab, const void* svb,
    const int* __restrict__ flag, float* __restrict__ c0)
{
    int f32 = *flag;
    int r2 = blockIdx.x, m = threadIdx.x;
    __shared__ float red[256];
    float acc = 0.f;
    #pragma unroll
    for (int i = 0; i < 7; ++i)
        acc += ldu(outb, i * 256 + m, f32) * gsum_load(i, r2, m, sl, sa, sv, f32);
    red[m] = acc;
    __syncthreads();
    for (int s = 128; s > 0; s >>= 1) {
        if (m < s) red[m] += red[m + s];
        __syncthreads();
    }
    if (m == 0)
        c0[r2] = red[0] + ldu(slb, r2, f32) + ldu(sab, r2, f32) + ldu(svb, r2, f32);
}

__global__ __launch_bounds__(256) void bias2_kernel(
    const float* __restrict__ c0, const void* finalw, const void* finalb,
    const int* __restrict__ flag, float* __restrict__ d0)
{
    int f32 = *flag;
    int e = blockIdx.x, r = threadIdx.x;
    __shared__ float red[256];
    red[r] = c0[r] * ldu(finalw, (size_t)e * 256 + r, f32);
    __syncthreads();
    for (int s = 128; s > 0; s >>= 1) {
        if (r < s) red[r] += red[r + s];
        __syncthreads();
    }
    if (r == 0)
        d0[e] = red[0] + ldu(finalb, e, f32);
}

// ---------------------------------------------------------------------------
// Kernel 4 (NEW, MFMA): result = O @ Dstack + d0 via 16x16x32 bf16 MFMA with
// split-precision (hi+lo) operands: C = Ah·Bh + Ah·Bl + Al·Bh (Al·Bl ~2^-18,
// dropped). No LDS: fragments loaded straight from global. Wave = one 16x16
// tile; grid (4 col-groups of 64, 192 row-groups of 16) x 4 waves.
// A-layout A[m=lane&15][k=quad*8+j]; B fed from transposed DT so the lane
// load pattern is identical; C/D: col=lane&15, row=quad*4+reg (guide §3).
// ---------------------------------------------------------------------------
__global__ __launch_bounds__(256) void final_gemm_mfma_kernel(
    const unsigned short* __restrict__ Ohi, const unsigned short* __restrict__ Olo,
    const unsigned short* __restrict__ DThi, const unsigned short* __restrict__ DTlo,
    const float* __restrict__ d0, const int* __restrict__ flag,
    void* __restrict__ outv)
{
    int f32 = *flag;
    int bx = blockIdx.x;          // col group 0..3 (64 cols)
    int by = blockIdx.y;          // row group 0..191 (16 rows)
    int w  = threadIdx.x >> 6;    // wave 0..3
    int lane = threadIdx.x & 63;
    int m = lane & 15, quad = lane >> 4;
    int R0 = by * 16, C0 = bx * 64 + w * 16;

    int t0 = R0 >> 2, t1 = (R0 + 15) >> 2;
    int g0 = (t0 < 300) ? 0 : (t0 < 550 ? 1 : 2);
    int g1 = (t1 < 300) ? 0 : (t1 < 550 ? 1 : 2);
    int activeset = (1 << g0) | (1 << g1);
    const int masks[7] = {7, 3, 5, 6, 1, 2, 4};

    const unsigned short* arow_h = Ohi + (size_t)(R0 + m) * 1792;
    const unsigned short* arow_l = Olo + (size_t)(R0 + m) * 1792;
    const unsigned short* brow_h = DThi + (size_t)(C0 + m) * 1792;
    const unsigned short* brow_l = DTlo + (size_t)(C0 + m) * 1792;
    int koff = quad * 8;

    f32x4 acc = {};
    for (int i = 0; i < 7; ++i) {
        if (!(masks[i] & activeset)) continue;   // O block exactly zero
        #pragma unroll
        for (int kb = 0; kb < 8; ++kb) {
            int k0 = i * 256 + kb * 32 + koff;
            bf16x8 ah = *(const bf16x8*)(arow_h + k0);
            bf16x8 al = *(const bf16x8*)(arow_l + k0);
            bf16x8 bh = *(const bf16x8*)(brow_h + k0);
            bf16x8 bl = *(const bf16x8*)(brow_l + k0);
            acc = __builtin_amdgcn_mfma_f32_16x16x32_bf16(ah, bh, acc, 0, 0, 0);
            acc = __builtin_amdgcn_mfma_f32_16x16x32_bf16(ah, bl, acc, 0, 0, 0);
            acc = __builtin_amdgcn_mfma_f32_16x16x32_bf16(al, bh, acc, 0, 0, 0);
        }
    }
    float dv = d0[C0 + m];
    #pragma unroll
    for (int r = 0; r < 4; ++r) {
        int row = R0 + quad * 4 + r;
        int col = C0 + m;
        float val = acc[r] + dv;
        if (f32) ((float*)outv)[(size_t)row * 256 + col] = val;
        else ((__hip_bfloat16*)outv)[(size_t)row * 256 + col] = __float2bfloat16(val);
    }
}

// ---------------------------------------------------------------------------
extern "C" void kernel_launch(void* const* d_in, const int* in_sizes, int n_in,
                              void* d_out, int out_size, void* d_ws, size_t ws_size,
                              hipStream_t stream) {
    const void* query     = d_in[0];
    const void* key       = d_in[1];
    const void* value     = d_in[2];
    const void* in_proj_w = d_in[3];
    const void* in_proj_b = d_in[4];
    const void* out_w     = d_in[5];
    const void* out_b     = d_in[6];
    const void* s_l_w     = d_in[7];
    const void* s_l_b     = d_in[8];
    const void* s_a_w     = d_in[9];
    const void* s_a_b     = d_in[10];
    const void* s_v_w     = d_in[11];
    const void* s_v_b     = d_in[12];
    const void* final_w   = d_in[13];
    const void* final_b   = d_in[14];

    float* ws     = (float*)d_ws;
    float* qws    = ws;                 //   786432 f
    float* kws    = ws + 786432;        //   786432 f
    float* vws    = ws + 1572864;       //   786432 f
    // O region (5505024 f = 22 MB) split into bf16 hi+lo planes (11MB each):
    unsigned short* Ohi = (unsigned short*)(ws + 2359296);   // 5505024 bf16
    unsigned short* Olo = (unsigned short*)(ws + 5111808);   // 5505024 bf16
    float* Mtmp   = ws + 7864320;       //   458752 f
    // Dstack region (458752 f = 1.8 MB) split into transposed bf16 hi+lo:
    unsigned short* DThi = (unsigned short*)(ws + 8323072);  // 458752 bf16
    unsigned short* DTlo = (unsigned short*)(ws + 8552448);  // 458752 bf16
    float* d0     = ws + 8781824;       //      256 f
    int*   flag   = (int*)(ws + 8782080);  // 1 int — proven footprint HIGH-WATER
    float* c0     = Mtmp;               // ALIAS: Mtmp dead after wcomb2

    detect_kernel<<<1, 64, 0, stream>>>((const unsigned short*)query, flag);
    qkv_gemm_kernel<<<dim3(12, 48), 256, 0, stream>>>(query, key, value,
                                                      in_proj_w, in_proj_b, flag,
                                                      qws, kws, vws);
    wcomb1_kernel<<<7 * 256, 256, 0, stream>>>(s_l_w, s_a_w, s_v_w, out_w, flag, Mtmp);
    attn_tiled_kernel<<<dim3(24, 32), 256, 0, stream>>>(qws, kws, vws, Ohi, Olo);
    wcomb2_gemm_kernel<<<dim3(4, 4, 7), 256, 0, stream>>>(Mtmp, final_w, flag,
                                                          DThi, DTlo);
    bias1_kernel<<<256, 256, 0, stream>>>(s_l_w, s_a_w, s_v_w, out_b,
                                          s_l_b, s_a_b, s_v_b, flag, c0);
    bias2_kernel<<<256, 256, 0, stream>>>(c0, final_w, final_b, flag, d0);
    final_gemm_mfma_kernel<<<dim3(4, 192), 256, 0, stream>>>(Ohi, Olo, DThi, DTlo,
                                                             d0, flag, d_out);
}

// Round 12
// 305.530 us; speedup vs baseline: 1.3218x; 1.0906x over previous
//
#include <hip/hip_runtime.h>
#include <hip/hip_bf16.h>

#define E 256
#define H 8
#define HD 32
#define T 768
#define B 4
#define BH 32
// segments: L=[0,300), A=[300,550), V=[550,768)

typedef __attribute__((ext_vector_type(8))) short bf16x8;
typedef __attribute__((ext_vector_type(4))) float f32x4;

__device__ __forceinline__ float b2f(__hip_bfloat16 x) { return __bfloat162float(x); }

__device__ __forceinline__ unsigned short f2bf_u(float x) {
    __hip_bfloat16 h = __float2bfloat16(x);
    return *(unsigned short*)&h;
}
__device__ __forceinline__ float bfu2f(unsigned short u) {
    return __uint_as_float(((unsigned int)u) << 16);
}

// dtype-agnostic scalar load: f32 ? float : bf16
__device__ __forceinline__ float ldu(const void* p, size_t i, int f32) {
    if (f32) return ((const float*)p)[i];
    return b2f(((const __hip_bfloat16*)p)[i]);
}

// ---------------------------------------------------------------------------
// Kernel 0: input dtype detection (fp32 read as bf16 -> garbage exponents).
// ---------------------------------------------------------------------------
__global__ void detect_kernel(const unsigned short* __restrict__ q,
                              int* __restrict__ flag) {
    if (threadIdx.x == 0 && blockIdx.x == 0) {
        int f32 = 0;
        for (int i = 0; i < 256; ++i) {
            unsigned int bits = ((unsigned int)q[i]) << 16;
            float v = __uint_as_float(bits);
            if (!(v == v) || fabsf(v) > 1e4f) f32 = 1;
        }
        *flag = f32;
    }
}

// ---------------------------------------------------------------------------
// Kernel 1: QKV projection, round-12 LDS-vectorized retile. A stored
// TRANSPOSED (AsT[kk][row], stride 68 for 16B alignment) so the inner loop is
// 2x ds_read_b128 per 16 FMA (A-read = 16-lane broadcast, B-read = 2-way,
// both free) instead of 8 scalar reads. Staging via float4 global loads.
// ---------------------------------------------------------------------------
__global__ __launch_bounds__(256) void qkv_gemm_kernel(
    const void* query, const void* key, const void* value,
    const void* w, const void* bias, const int* __restrict__ flag,
    float* __restrict__ qws, float* __restrict__ kws, float* __restrict__ vws)
{
    int f32 = *flag;
    int bx = blockIdx.x;              // 0..11 col tiles
    int by = blockIdx.y;              // 0..47 row tiles
    int sec = bx >> 2;                // 0=q, 1=k, 2=v
    const void* X = (sec == 0) ? query : (sec == 1) ? key : value;
    int colbase = bx * 64;
    int rowbase = by * 64;
    int tid = threadIdx.x;
    int tx = tid & 15, ty = tid >> 4;
    __shared__ __align__(16) float AsT[32][68];   // [kk][row]
    __shared__ __align__(16) float Bs[32][68];    // [kk][col]
    float acc[4][4] = {};

    for (int kb = 0; kb < 8; ++kb) {
        __syncthreads();
        if (f32) {
            const float4* Xg = (const float4*)((const float*)X +
                                (size_t)rowbase * 256 + kb * 32);
            const float4* Wg = (const float4*)((const float*)w +
                                (size_t)colbase * 256 + kb * 32);
            #pragma unroll
            for (int l = 0; l < 2; ++l) {
                int idx4 = l * 256 + tid;
                int r = idx4 >> 3, kq = idx4 & 7;   // row/col 0..63, k-quad 0..7
                float4 xv = Xg[(size_t)r * 64 + kq];
                AsT[kq * 4 + 0][r] = xv.x;
                AsT[kq * 4 + 1][r] = xv.y;
                AsT[kq * 4 + 2][r] = xv.z;
                AsT[kq * 4 + 3][r] = xv.w;
                float4 wv = Wg[(size_t)r * 64 + kq];
                Bs[kq * 4 + 0][r] = wv.x;
                Bs[kq * 4 + 1][r] = wv.y;
                Bs[kq * 4 + 2][r] = wv.z;
                Bs[kq * 4 + 3][r] = wv.w;
            }
        } else {
            #pragma unroll
            for (int l = 0; l < 2; ++l) {
                int idx4 = l * 256 + tid;
                int r = idx4 >> 3, kq = idx4 & 7;
                #pragma unroll
                for (int j = 0; j < 4; ++j) {
                    AsT[kq * 4 + j][r] =
                        ldu(X, (size_t)(rowbase + r) * 256 + kb * 32 + kq * 4 + j, 0);
                    Bs[kq * 4 + j][r] =
                        ldu(w, (size_t)(colbase + r) * 256 + kb * 32 + kq * 4 + j, 0);
                }
            }
        }
        __syncthreads();
        #pragma unroll 8
        for (int kk = 0; kk < 32; ++kk) {
            const float4 av = *(const float4*)&AsT[kk][ty * 4];
            const float4 bv = *(const float4*)&Bs[kk][tx * 4];
            acc[0][0] += av.x * bv.x; acc[0][1] += av.x * bv.y;
            acc[0][2] += av.x * bv.z; acc[0][3] += av.x * bv.w;
            acc[1][0] += av.y * bv.x; acc[1][1] += av.y * bv.y;
            acc[1][2] += av.y * bv.z; acc[1][3] += av.y * bv.w;
            acc[2][0] += av.z * bv.x; acc[2][1] += av.z * bv.y;
            acc[2][2] += av.z * bv.z; acc[2][3] += av.z * bv.w;
            acc[3][0] += av.w * bv.x; acc[3][1] += av.w * bv.y;
            acc[3][2] += av.w * bv.z; acc[3][3] += av.w * bv.w;
        }
    }
    float* dst = (sec == 0) ? qws : (sec == 1) ? kws : vws;
    #pragma unroll
    for (int u = 0; u < 4; ++u)
        #pragma unroll
        for (int v = 0; v < 4; ++v) {
            int r = rowbase + ty * 4 + u;          // t*B + b
            int cg = colbase + tx * 4 + v;         // 0..767
            float val = acc[u][v] + ldu(bias, cg, f32);
            if (sec == 0) val *= 0.17677669529663687f;  // HD^-0.5
            int e_local = cg & 255;
            int h = e_local >> 5, hd = e_local & 31;
            int t = r >> 2, b = r & 3;
            dst[((size_t)((b * H + h) * T + t)) * HD + hd] = val;
        }
}

// ---------------------------------------------------------------------------
// Kernel 2: attention (proven round-11: transposed LDS + bf16 hi/lo epilogue).
// ---------------------------------------------------------------------------
#define Q_OFF 0      // q_sT [32 hd][36]  (col = t-row)
#define K_OFF 1152   // k_sT [32 hd][68]  (col = s-col)
#define V_OFF 3328   // v_s  [64 s][36]   (col = hd)
#define E_OFF 5632   // e_sT [64 s][36]   (col = t-row)
#define S_OFF 7936   // S_s  [32 t][3]
#define R_OFF 1152   // red4 [4 wave][32 t][36] — epilogue only, aliases k/v/e

#define PV4(SEG)                                                            \
    {                                                                       \
        const float4 e4 = *(const float4*)&smem[E_OFF + ss * 36 + tq * 4];  \
        const float4 v4 = *(const float4*)&smem[V_OFF + ss * 36 + hq * 4];  \
        pacc[SEG][0][0] += e4.x * v4.x; pacc[SEG][0][1] += e4.x * v4.y;     \
        pacc[SEG][0][2] += e4.x * v4.z; pacc[SEG][0][3] += e4.x * v4.w;     \
        pacc[SEG][1][0] += e4.y * v4.x; pacc[SEG][1][1] += e4.y * v4.y;     \
        pacc[SEG][1][2] += e4.y * v4.z; pacc[SEG][1][3] += e4.y * v4.w;     \
        pacc[SEG][2][0] += e4.z * v4.x; pacc[SEG][2][1] += e4.z * v4.y;     \
        pacc[SEG][2][2] += e4.z * v4.z; pacc[SEG][2][3] += e4.z * v4.w;     \
        pacc[SEG][3][0] += e4.w * v4.x; pacc[SEG][3][1] += e4.w * v4.y;     \
        pacc[SEG][3][2] += e4.w * v4.z; pacc[SEG][3][3] += e4.w * v4.w;     \
    }

__global__ __launch_bounds__(256) void attn_tiled_kernel(
    const float* __restrict__ qws, const float* __restrict__ kws,
    const float* __restrict__ vws,
    unsigned short* __restrict__ Ohi, unsigned short* __restrict__ Olo)
{
    int tile = blockIdx.x;       // 0..23
    int bh   = blockIdx.y;       // 0..31
    int t0 = tile * 32;
    int tid = threadIdx.x;
    int tx = tid & 15, ty = tid >> 4;        // Phase A layout
    int wv = tid >> 6;                       // wave id 0..3 (Phase B ss-quarter)
    int tq = tid & 7, hq = (tid >> 3) & 7;   // Phase B layout (t-quad, hd-quad)

    __shared__ __align__(16) float smem[8032];

    // Stage q transposed: q_sT[hd][t]
    const float* qbase = qws + ((size_t)bh * T + t0) * HD;
    #pragma unroll
    for (int l = 0; l < 4; ++l) {
        int idx = l * 256 + tid;             // t*32 + hd
        smem[Q_OFF + (idx & 31) * 36 + (idx >> 5)] = qbase[idx];
    }

    float pacc[3][4][4] = {};   // [seg][t-row in quad][hd in quad], ss-quarter partial
    float ssum[3][2] = {};      // Phase A layout: [seg][t-row pair]

    const float* kbase = kws + (size_t)bh * T * HD;
    const float* vbase = vws + (size_t)bh * T * HD;

    for (int ch = 0; ch < 12; ++ch) {
        int base = ch * 64;
        __syncthreads();
        const float4* kg = (const float4*)(kbase + (size_t)base * HD);
        const float4* vg = (const float4*)(vbase + (size_t)base * HD);
        #pragma unroll
        for (int l2 = 0; l2 < 2; ++l2) {
            int idx4 = l2 * 256 + tid;       // s*8 + h4
            int s = idx4 >> 3, h4 = (idx4 & 7) * 4;
            float4 kq = kg[idx4];
            smem[K_OFF + (h4 + 0) * 68 + s] = kq.x;
            smem[K_OFF + (h4 + 1) * 68 + s] = kq.y;
            smem[K_OFF + (h4 + 2) * 68 + s] = kq.z;
            smem[K_OFF + (h4 + 3) * 68 + s] = kq.w;
            *(float4*)&smem[V_OFF + s * 36 + h4] = vg[idx4];
        }
        __syncthreads();

        // Phase A: 2x4 score tile; per kk: 1 b64 (q pair) + 1 b128 (k quad).
        float sc[2][4] = {};
        #pragma unroll 8
        for (int kk = 0; kk < 32; ++kk) {
            const float2 qv = *(const float2*)&smem[Q_OFF + kk * 36 + ty * 2];
            const float4 kv = *(const float4*)&smem[K_OFF + kk * 68 + tx * 4];
            sc[0][0] += qv.x * kv.x; sc[0][1] += qv.x * kv.y;
            sc[0][2] += qv.x * kv.z; sc[0][3] += qv.x * kv.w;
            sc[1][0] += qv.y * kv.x; sc[1][1] += qv.y * kv.y;
            sc[1][2] += qv.y * kv.z; sc[1][3] += qv.y * kv.w;
        }
        #pragma unroll
        for (int u = 0; u < 2; ++u)
            #pragma unroll
            for (int vv = 0; vv < 4; ++vv) {
                float e = __expf(sc[u][vv]);
                int sg = base + tx * 4 + vv;
                if (sg < 300) ssum[0][u] += e;
                else if (sg < 550) ssum[1][u] += e;
                else ssum[2][u] += e;
                smem[E_OFF + (tx * 4 + vv) * 36 + ty * 2 + u] = e;  // e_sT[s][t]
            }
        __syncthreads();

        // Phase B: wave wv covers ss in [wv*16, wv*16+16); uniform seg bounds.
        int e0 = min(max(300 - base, 0), 64);
        int e1 = min(max(550 - base, 0), 64);
        int lo = wv * 16, hi = lo + 16;
        for (int ss = lo, z = min(hi, e0); ss < z; ++ss) PV4(0)
        for (int ss = max(lo, e0), z = min(hi, e1); ss < z; ++ss) PV4(1)
        for (int ss = max(lo, e1); ss < hi; ++ss) PV4(2)
    }

    // Reduce ssum across tx (Phase A layout) -> S_s[t][seg].
    #pragma unroll
    for (int sg = 0; sg < 3; ++sg)
        #pragma unroll
        for (int u = 0; u < 2; ++u) {
            float v = ssum[sg][u];
            v += __shfl_down(v, 8, 16);
            v += __shfl_down(v, 4, 16);
            v += __shfl_down(v, 2, 16);
            v += __shfl_down(v, 1, 16);
            if (tx == 0) smem[S_OFF + (ty * 2 + u) * 3 + sg] = v;
        }
    __syncthreads();   // all Phase B done -> staging region dead; S_s visible

    // Cross-wave pacc reduction via red4 (aliased), one seg at a time.
    int tt = tid >> 3, q4 = tid & 7;       // epilogue layout: t-row, hd-quad
    float Pv[3][4];
    #pragma unroll
    for (int sg = 0; sg < 3; ++sg) {
        #pragma unroll
        for (int u = 0; u < 4; ++u)
            #pragma unroll
            for (int j = 0; j < 4; ++j)
                smem[R_OFF + wv * 1152 + (tq * 4 + u) * 36 + hq * 4 + j] =
                    pacc[sg][u][j];
        __syncthreads();
        float s0 = 0.f, s1 = 0.f, s2 = 0.f, s3 = 0.f;
        #pragma unroll
        for (int w = 0; w < 4; ++w) {
            const float4 r = *(const float4*)&smem[R_OFF + w * 1152 + tt * 36 + q4 * 4];
            s0 += r.x; s1 += r.y; s2 += r.z; s3 += r.w;
        }
        Pv[sg][0] = s0; Pv[sg][1] = s1; Pv[sg][2] = s2; Pv[sg][3] = s3;
        __syncthreads();
    }

    // Epilogue: 7 branch outputs, bf16 hi+lo (8B stores each).
    int t_glob = t0 + tt;
    int g = (t_glob < 300) ? 0 : (t_glob < 550 ? 1 : 2);
    float S0 = smem[S_OFF + tt * 3 + 0];
    float S1 = smem[S_OFF + tt * 3 + 1];
    float S2 = smem[S_OFF + tt * 3 + 2];
    int b = bh >> 3, h = bh & 7;
    size_t obase = (size_t)(t_glob * B + b) * 1792 + h * 32 + q4 * 4;
    const int masks[7] = {7, 3, 5, 6, 1, 2, 4};  // LAV,LA,LV,AV,L,A,V
    #pragma unroll
    for (int i = 0; i < 7; ++i) {
        int m = masks[i];
        float n0 = 0.f, n1 = 0.f, n2 = 0.f, n3 = 0.f, den = 0.f;
        if (m & 1) { n0 += Pv[0][0]; n1 += Pv[0][1]; n2 += Pv[0][2]; n3 += Pv[0][3]; den += S0; }
        if (m & 2) { n0 += Pv[1][0]; n1 += Pv[1][1]; n2 += Pv[1][2]; n3 += Pv[1][3]; den += S1; }
        if (m & 4) { n0 += Pv[2][0]; n1 += Pv[2][1]; n2 += Pv[2][2]; n3 += Pv[2][3]; den += S2; }
        float r = 1.f / den;
        int live = (m >> g) & 1;
        float o[4];
        o[0] = live ? n0 * r : 0.f;
        o[1] = live ? n1 * r : 0.f;
        o[2] = live ? n2 * r : 0.f;
        o[3] = live ? n3 * r : 0.f;
        ushort4 hi4, lo4;
        unsigned short* hp = (unsigned short*)&hi4;
        unsigned short* lp = (unsigned short*)&lo4;
        #pragma unroll
        for (int j = 0; j < 4; ++j) {
            unsigned short hu = f2bf_u(o[j]);
            hp[j] = hu;
            lp[j] = f2bf_u(o[j] - bfu2f(hu));
        }
        *(ushort4*)&Ohi[obase + (size_t)i * 256] = hi4;
        *(ushort4*)&Olo[obase + (size_t)i * 256] = lo4;
    }
}

// ---------------------------------------------------------------------------
// Weight combination: D_i = (final_w @ G_i @ out_w[i])^T stacked as (1792,256).
// ---------------------------------------------------------------------------
__device__ __forceinline__ float gsum_load(int i, int r2, int r,
                                           const void* sl, const void* sa,
                                           const void* sv, int f32)
{
    size_t base = (size_t)r2 * 1024;
    switch (i) {
        case 0: return ldu(sl, base + r, f32) + ldu(sa, base + r, f32) + ldu(sv, base + r, f32);
        case 1: return ldu(sl, base + 256 + r, f32) + ldu(sa, base + 256 + r, f32);
        case 2: return ldu(sl, base + 512 + r, f32) + ldu(sv, base + 256 + r, f32);
        case 3: return ldu(sa, base + 512 + r, f32) + ldu(sv, base + 512 + r, f32);
        case 4: return ldu(sl, base + 768 + r, f32);
        case 5: return ldu(sa, base + 768 + r, f32);
        default: return ldu(sv, base + 768 + r, f32);
    }
}

// Mtmp_i = G_i @ out_w[i]    (proven round-2)
__global__ __launch_bounds__(256) void wcomb1_kernel(
    const void* sl, const void* sa, const void* sv, const void* outw,
    const int* __restrict__ flag, float* __restrict__ Mtmp)
{
    int f32 = *flag;
    int bid = blockIdx.x;
    int i = bid >> 8, r2 = bid & 255;
    int c = threadIdx.x;
    __shared__ float g[256];
    g[c] = gsum_load(i, r2, c, sl, sa, sv, f32);
    __syncthreads();
    float acc = 0.f;
    for (int r = 0; r < 256; ++r)
        acc += g[r] * ldu(outw, (size_t)i * 65536 + r * 256 + c, f32);
    Mtmp[(size_t)i * 65536 + r2 * 256 + c] = acc;
}

// Dstack as TRANSPOSED bf16 hi+lo planes: DT[e][i*256+c], e in [0,256).
__global__ __launch_bounds__(256) void wcomb2_gemm_kernel(
    const float* __restrict__ Mtmp, const void* finalw,
    const int* __restrict__ flag,
    unsigned short* __restrict__ DThi, unsigned short* __restrict__ DTlo)
{
    int f32 = *flag;
    int bx = blockIdx.x;   // col tile 0..3 (e)
    int by = blockIdx.y;   // row tile 0..3 (c)
    int i  = blockIdx.z;   // branch 0..6
    int tid = threadIdx.x;
    int tx = tid & 15, ty = tid >> 4;
    int colbase = bx * 64, rowbase = by * 64;
    __shared__ float As[64][33];   // Mtmp^T [c][j]
    __shared__ float Bs[32][65];   // finalw^T [j][e]
    float acc[4][4] = {};

    for (int kb = 0; kb < 8; ++kb) {
        __syncthreads();
        #pragma unroll
        for (int l = 0; l < 8; ++l) {
            int idx = l * 256 + tid;
            int r = idx & 63, kk = idx >> 6;      // r contiguous -> coalesced
            As[r][kk] = Mtmp[(size_t)i * 65536 + (kb * 32 + kk) * 256 + rowbase + r];
            int n = idx >> 5, k2 = idx & 31;      // k2 contiguous -> coalesced
            Bs[k2][n] = ldu(finalw, (size_t)(colbase + n) * 256 + kb * 32 + k2, f32);
        }
        __syncthreads();
        #pragma unroll 8
        for (int kk = 0; kk < 32; ++kk) {
            float av[4], bv[4];
            #pragma unroll
            for (int u = 0; u < 4; ++u) av[u] = As[ty * 4 + u][kk];
            #pragma unroll
            for (int v = 0; v < 4; ++v) bv[v] = Bs[kk][tx * 4 + v];
            #pragma unroll
            for (int u = 0; u < 4; ++u)
                #pragma unroll
                for (int v = 0; v < 4; ++v)
                    acc[u][v] += av[u] * bv[v];
        }
    }
    #pragma unroll
    for (int u = 0; u < 4; ++u)
        #pragma unroll
        for (int v = 0; v < 4; ++v) {
            int c = rowbase + ty * 4 + u, e = colbase + tx * 4 + v;
            float a = acc[u][v];
            unsigned short hu = f2bf_u(a);
            DThi[(size_t)e * 1792 + i * 256 + c] = hu;
            DTlo[(size_t)e * 1792 + i * 256 + c] = f2bf_u(a - bfu2f(hu));
        }
}

// ---------------------------------------------------------------------------
// Bias path (proven round-5). c0 ALIASES Mtmp (dead after wcomb2).
// ws footprint unchanged from proven layout — do NOT grow it.
// ---------------------------------------------------------------------------
__global__ __launch_bounds__(256) void bias1_kernel(
    const void* sl, const void* sa, const void* sv, const void* outb,
    const void* slb, const void* sab, const void* svb,
    const int* __restrict__ flag, float* __restrict__ c0)
{
    int f32 = *flag;
    int r2 = blockIdx.x, m = threadIdx.x;
    __shared__ float red[256];
    float acc = 0.f;
    #pragma unroll
    for (int i = 0; i < 7; ++i)
        acc += ldu(outb, i * 256 + m, f32) * gsum_load(i, r2, m, sl, sa, sv, f32);
    red[m] = acc;
    __syncthreads();
    for (int s = 128; s > 0; s >>= 1) {
        if (m < s) red[m] += red[m + s];
        __syncthreads();
    }
    if (m == 0)
        c0[r2] = red[0] + ldu(slb, r2, f32) + ldu(sab, r2, f32) + ldu(svb, r2, f32);
}

__global__ __launch_bounds__(256) void bias2_kernel(
    const float* __restrict__ c0, const void* finalw, const void* finalb,
    const int* __restrict__ flag, float* __restrict__ d0)
{
    int f32 = *flag;
    int e = blockIdx.x, r = threadIdx.x;
    __shared__ float red[256];
    red[r] = c0[r] * ldu(finalw, (size_t)e * 256 + r, f32);
    __syncthreads();
    for (int s = 128; s > 0; s >>= 1) {
        if (r < s) red[r] += red[r + s];
        __syncthreads();
    }
    if (r == 0)
        d0[e] = red[0] + ldu(finalb, e, f32);
}

// ---------------------------------------------------------------------------
// Kernel 4 (proven round-11, MFMA): result = O @ Dstack + d0 via 16x16x32
// bf16 MFMA, split-precision hi+lo operands, no LDS.
// ---------------------------------------------------------------------------
__global__ __launch_bounds__(256) void final_gemm_mfma_kernel(
    const unsigned short* __restrict__ Ohi, const unsigned short* __restrict__ Olo,
    const unsigned short* __restrict__ DThi, const unsigned short* __restrict__ DTlo,
    const float* __restrict__ d0, const int* __restrict__ flag,
    void* __restrict__ outv)
{
    int f32 = *flag;
    int bx = blockIdx.x;          // col group 0..3 (64 cols)
    int by = blockIdx.y;          // row group 0..191 (16 rows)
    int w  = threadIdx.x >> 6;    // wave 0..3
    int lane = threadIdx.x & 63;
    int m = lane & 15, quad = lane >> 4;
    int R0 = by * 16, C0 = bx * 64 + w * 16;

    int t0 = R0 >> 2, t1 = (R0 + 15) >> 2;
    int g0 = (t0 < 300) ? 0 : (t0 < 550 ? 1 : 2);
    int g1 = (t1 < 300) ? 0 : (t1 < 550 ? 1 : 2);
    int activeset = (1 << g0) | (1 << g1);
    const int masks[7] = {7, 3, 5, 6, 1, 2, 4};

    const unsigned short* arow_h = Ohi + (size_t)(R0 + m) * 1792;
    const unsigned short* arow_l = Olo + (size_t)(R0 + m) * 1792;
    const unsigned short* brow_h = DThi + (size_t)(C0 + m) * 1792;
    const unsigned short* brow_l = DTlo + (size_t)(C0 + m) * 1792;
    int koff = quad * 8;

    f32x4 acc = {};
    for (int i = 0; i < 7; ++i) {
        if (!(masks[i] & activeset)) continue;   // O block exactly zero
        #pragma unroll
        for (int kb = 0; kb < 8; ++kb) {
            int k0 = i * 256 + kb * 32 + koff;
            bf16x8 ah = *(const bf16x8*)(arow_h + k0);
            bf16x8 al = *(const bf16x8*)(arow_l + k0);
            bf16x8 bh = *(const bf16x8*)(brow_h + k0);
            bf16x8 bl = *(const bf16x8*)(brow_l + k0);
            acc = __builtin_amdgcn_mfma_f32_16x16x32_bf16(ah, bh, acc, 0, 0, 0);
            acc = __builtin_amdgcn_mfma_f32_16x16x32_bf16(ah, bl, acc, 0, 0, 0);
            acc = __builtin_amdgcn_mfma_f32_16x16x32_bf16(al, bh, acc, 0, 0, 0);
        }
    }
    float dv = d0[C0 + m];
    #pragma unroll
    for (int r = 0; r < 4; ++r) {
        int row = R0 + quad * 4 + r;
        int col = C0 + m;
        float val = acc[r] + dv;
        if (f32) ((float*)outv)[(size_t)row * 256 + col] = val;
        else ((__hip_bfloat16*)outv)[(size_t)row * 256 + col] = __float2bfloat16(val);
    }
}

// ---------------------------------------------------------------------------
extern "C" void kernel_launch(void* const* d_in, const int* in_sizes, int n_in,
                              void* d_out, int out_size, void* d_ws, size_t ws_size,
                              hipStream_t stream) {
    const void* query     = d_in[0];
    const void* key       = d_in[1];
    const void* value     = d_in[2];
    const void* in_proj_w = d_in[3];
    const void* in_proj_b = d_in[4];
    const void* out_w     = d_in[5];
    const void* out_b     = d_in[6];
    const void* s_l_w     = d_in[7];
    const void* s_l_b     = d_in[8];
    const void* s_a_w     = d_in[9];
    const void* s_a_b     = d_in[10];
    const void* s_v_w     = d_in[11];
    const void* s_v_b     = d_in[12];
    const void* final_w   = d_in[13];
    const void* final_b   = d_in[14];

    float* ws     = (float*)d_ws;
    float* qws    = ws;                 //   786432 f
    float* kws    = ws + 786432;        //   786432 f
    float* vws    = ws + 1572864;       //   786432 f
    // O region (5505024 f = 22 MB) split into bf16 hi+lo planes (11MB each):
    unsigned short* Ohi = (unsigned short*)(ws + 2359296);   // 5505024 bf16
    unsigned short* Olo = (unsigned short*)(ws + 5111808);   // 5505024 bf16
    float* Mtmp   = ws + 7864320;       //   458752 f
    // Dstack region (458752 f = 1.8 MB) split into transposed bf16 hi+lo:
    unsigned short* DThi = (unsigned short*)(ws + 8323072);  // 458752 bf16
    unsigned short* DTlo = (unsigned short*)(ws + 8552448);  // 458752 bf16
    float* d0     = ws + 8781824;       //      256 f
    int*   flag   = (int*)(ws + 8782080);  // 1 int — proven footprint HIGH-WATER
    float* c0     = Mtmp;               // ALIAS: Mtmp dead after wcomb2

    detect_kernel<<<1, 64, 0, stream>>>((const unsigned short*)query, flag);
    qkv_gemm_kernel<<<dim3(12, 48), 256, 0, stream>>>(query, key, value,
                                                      in_proj_w, in_proj_b, flag,
                                                      qws, kws, vws);
    wcomb1_kernel<<<7 * 256, 256, 0, stream>>>(s_l_w, s_a_w, s_v_w, out_w, flag, Mtmp);
    attn_tiled_kernel<<<dim3(24, 32), 256, 0, stream>>>(qws, kws, vws, Ohi, Olo);
    wcomb2_gemm_kernel<<<dim3(4, 4, 7), 256, 0, stream>>>(Mtmp, final_w, flag,
                                                          DThi, DTlo);
    bias1_kernel<<<256, 256, 0, stream>>>(s_l_w, s_a_w, s_v_w, out_b,
                                          s_l_b, s_a_b, s_v_b, flag, c0);
    bias2_kernel<<<256, 256, 0, stream>>>(c0, final_w, final_b, flag, d0);
    final_gemm_mfma_kernel<<<dim3(4, 192), 256, 0, stream>>>(Ohi, Olo, DThi, DTlo,
                                                             d0, flag, d_out);
}

// Round 13
// 278.482 us; speedup vs baseline: 1.4502x; 1.0971x over previous
//
#include <hip/hip_runtime.h>
#include <hip/hip_bf16.h>

#define E 256
#define H 8
#define HD 32
#define T 768
#define B 4
#define BH 32
// segments: L=[0,300), A=[300,550), V=[550,768)

typedef __attribute__((ext_vector_type(8))) short bf16x8;
typedef __attribute__((ext_vector_type(4))) float f32x4;

__device__ __forceinline__ float b2f(__hip_bfloat16 x) { return __bfloat162float(x); }

__device__ __forceinline__ unsigned short f2bf_u(float x) {
    __hip_bfloat16 h = __float2bfloat16(x);
    return *(unsigned short*)&h;
}
__device__ __forceinline__ float bfu2f(unsigned short u) {
    return __uint_as_float(((unsigned int)u) << 16);
}

// dtype-agnostic scalar load: f32 ? float : bf16
__device__ __forceinline__ float ldu(const void* p, size_t i, int f32) {
    if (f32) return ((const float*)p)[i];
    return b2f(((const __hip_bfloat16*)p)[i]);
}

// ---------------------------------------------------------------------------
// Fragment-major layout for MFMA operands (round 13):
//   buf[rowblk][kblk56][lane64][8]  — lane = (row&15) | (((k>>3)&3)<<4), j=k&7
// A wave's A/B fragment load is then base + lane*8: 1KB contiguous (16
// consecutive cache lines) instead of 16 scattered rows (r12's hidden 64us).
// ---------------------------------------------------------------------------

// ---------------------------------------------------------------------------
// Kernel 0: input dtype detection (fp32 read as bf16 -> garbage exponents).
// ---------------------------------------------------------------------------
__global__ void detect_kernel(const unsigned short* __restrict__ q,
                              int* __restrict__ flag) {
    if (threadIdx.x == 0 && blockIdx.x == 0) {
        int f32 = 0;
        for (int i = 0; i < 256; ++i) {
            unsigned int bits = ((unsigned int)q[i]) << 16;
            float v = __uint_as_float(bits);
            if (!(v == v) || fabsf(v) > 1e4f) f32 = 1;
        }
        *flag = f32;
    }
}

// ---------------------------------------------------------------------------
// Kernel 1: QKV projection (proven round-12 LDS-vectorized retile).
// ---------------------------------------------------------------------------
__global__ __launch_bounds__(256) void qkv_gemm_kernel(
    const void* query, const void* key, const void* value,
    const void* w, const void* bias, const int* __restrict__ flag,
    float* __restrict__ qws, float* __restrict__ kws, float* __restrict__ vws)
{
    int f32 = *flag;
    int bx = blockIdx.x;              // 0..11 col tiles
    int by = blockIdx.y;              // 0..47 row tiles
    int sec = bx >> 2;                // 0=q, 1=k, 2=v
    const void* X = (sec == 0) ? query : (sec == 1) ? key : value;
    int colbase = bx * 64;
    int rowbase = by * 64;
    int tid = threadIdx.x;
    int tx = tid & 15, ty = tid >> 4;
    __shared__ __align__(16) float AsT[32][68];   // [kk][row]
    __shared__ __align__(16) float Bs[32][68];    // [kk][col]
    float acc[4][4] = {};

    for (int kb = 0; kb < 8; ++kb) {
        __syncthreads();
        if (f32) {
            const float4* Xg = (const float4*)((const float*)X +
                                (size_t)rowbase * 256 + kb * 32);
            const float4* Wg = (const float4*)((const float*)w +
                                (size_t)colbase * 256 + kb * 32);
            #pragma unroll
            for (int l = 0; l < 2; ++l) {
                int idx4 = l * 256 + tid;
                int r = idx4 >> 3, kq = idx4 & 7;   // row/col 0..63, k-quad 0..7
                float4 xv = Xg[(size_t)r * 64 + kq];
                AsT[kq * 4 + 0][r] = xv.x;
                AsT[kq * 4 + 1][r] = xv.y;
                AsT[kq * 4 + 2][r] = xv.z;
                AsT[kq * 4 + 3][r] = xv.w;
                float4 wv = Wg[(size_t)r * 64 + kq];
                Bs[kq * 4 + 0][r] = wv.x;
                Bs[kq * 4 + 1][r] = wv.y;
                Bs[kq * 4 + 2][r] = wv.z;
                Bs[kq * 4 + 3][r] = wv.w;
            }
        } else {
            #pragma unroll
            for (int l = 0; l < 2; ++l) {
                int idx4 = l * 256 + tid;
                int r = idx4 >> 3, kq = idx4 & 7;
                #pragma unroll
                for (int j = 0; j < 4; ++j) {
                    AsT[kq * 4 + j][r] =
                        ldu(X, (size_t)(rowbase + r) * 256 + kb * 32 + kq * 4 + j, 0);
                    Bs[kq * 4 + j][r] =
                        ldu(w, (size_t)(colbase + r) * 256 + kb * 32 + kq * 4 + j, 0);
                }
            }
        }
        __syncthreads();
        #pragma unroll 8
        for (int kk = 0; kk < 32; ++kk) {
            const float4 av = *(const float4*)&AsT[kk][ty * 4];
            const float4 bv = *(const float4*)&Bs[kk][tx * 4];
            acc[0][0] += av.x * bv.x; acc[0][1] += av.x * bv.y;
            acc[0][2] += av.x * bv.z; acc[0][3] += av.x * bv.w;
            acc[1][0] += av.y * bv.x; acc[1][1] += av.y * bv.y;
            acc[1][2] += av.y * bv.z; acc[1][3] += av.y * bv.w;
            acc[2][0] += av.z * bv.x; acc[2][1] += av.z * bv.y;
            acc[2][2] += av.z * bv.z; acc[2][3] += av.z * bv.w;
            acc[3][0] += av.w * bv.x; acc[3][1] += av.w * bv.y;
            acc[3][2] += av.w * bv.z; acc[3][3] += av.w * bv.w;
        }
    }
    float* dst = (sec == 0) ? qws : (sec == 1) ? kws : vws;
    #pragma unroll
    for (int u = 0; u < 4; ++u)
        #pragma unroll
        for (int v = 0; v < 4; ++v) {
            int r = rowbase + ty * 4 + u;          // t*B + b
            int cg = colbase + tx * 4 + v;         // 0..767
            float val = acc[u][v] + ldu(bias, cg, f32);
            if (sec == 0) val *= 0.17677669529663687f;  // HD^-0.5
            int e_local = cg & 255;
            int h = e_local >> 5, hd = e_local & 31;
            int t = r >> 2, b = r & 3;
            dst[((size_t)((b * H + h) * T + t)) * HD + hd] = val;
        }
}

// ---------------------------------------------------------------------------
// Kernel 2: attention (proven round-11 core); epilogue stores O hi/lo in
// FRAGMENT-MAJOR layout for the MFMA final GEMM.
// ---------------------------------------------------------------------------
#define Q_OFF 0      // q_sT [32 hd][36]  (col = t-row)
#define K_OFF 1152   // k_sT [32 hd][68]  (col = s-col)
#define V_OFF 3328   // v_s  [64 s][36]   (col = hd)
#define E_OFF 5632   // e_sT [64 s][36]   (col = t-row)
#define S_OFF 7936   // S_s  [32 t][3]
#define R_OFF 1152   // red4 [4 wave][32 t][36] — epilogue only, aliases k/v/e

#define PV4(SEG)                                                            \
    {                                                                       \
        const float4 e4 = *(const float4*)&smem[E_OFF + ss * 36 + tq * 4];  \
        const float4 v4 = *(const float4*)&smem[V_OFF + ss * 36 + hq * 4];  \
        pacc[SEG][0][0] += e4.x * v4.x; pacc[SEG][0][1] += e4.x * v4.y;     \
        pacc[SEG][0][2] += e4.x * v4.z; pacc[SEG][0][3] += e4.x * v4.w;     \
        pacc[SEG][1][0] += e4.y * v4.x; pacc[SEG][1][1] += e4.y * v4.y;     \
        pacc[SEG][1][2] += e4.y * v4.z; pacc[SEG][1][3] += e4.y * v4.w;     \
        pacc[SEG][2][0] += e4.z * v4.x; pacc[SEG][2][1] += e4.z * v4.y;     \
        pacc[SEG][2][2] += e4.z * v4.z; pacc[SEG][2][3] += e4.z * v4.w;     \
        pacc[SEG][3][0] += e4.w * v4.x; pacc[SEG][3][1] += e4.w * v4.y;     \
        pacc[SEG][3][2] += e4.w * v4.z; pacc[SEG][3][3] += e4.w * v4.w;     \
    }

__global__ __launch_bounds__(256) void attn_tiled_kernel(
    const float* __restrict__ qws, const float* __restrict__ kws,
    const float* __restrict__ vws,
    unsigned short* __restrict__ Ohi, unsigned short* __restrict__ Olo)
{
    int tile = blockIdx.x;       // 0..23
    int bh   = blockIdx.y;       // 0..31
    int t0 = tile * 32;
    int tid = threadIdx.x;
    int tx = tid & 15, ty = tid >> 4;        // Phase A layout
    int wv = tid >> 6;                       // wave id 0..3 (Phase B ss-quarter)
    int tq = tid & 7, hq = (tid >> 3) & 7;   // Phase B layout (t-quad, hd-quad)

    __shared__ __align__(16) float smem[8032];

    // Stage q transposed: q_sT[hd][t]
    const float* qbase = qws + ((size_t)bh * T + t0) * HD;
    #pragma unroll
    for (int l = 0; l < 4; ++l) {
        int idx = l * 256 + tid;             // t*32 + hd
        smem[Q_OFF + (idx & 31) * 36 + (idx >> 5)] = qbase[idx];
    }

    float pacc[3][4][4] = {};   // [seg][t-row in quad][hd in quad], ss-quarter partial
    float ssum[3][2] = {};      // Phase A layout: [seg][t-row pair]

    const float* kbase = kws + (size_t)bh * T * HD;
    const float* vbase = vws + (size_t)bh * T * HD;

    for (int ch = 0; ch < 12; ++ch) {
        int base = ch * 64;
        __syncthreads();
        const float4* kg = (const float4*)(kbase + (size_t)base * HD);
        const float4* vg = (const float4*)(vbase + (size_t)base * HD);
        #pragma unroll
        for (int l2 = 0; l2 < 2; ++l2) {
            int idx4 = l2 * 256 + tid;       // s*8 + h4
            int s = idx4 >> 3, h4 = (idx4 & 7) * 4;
            float4 kq = kg[idx4];
            smem[K_OFF + (h4 + 0) * 68 + s] = kq.x;
            smem[K_OFF + (h4 + 1) * 68 + s] = kq.y;
            smem[K_OFF + (h4 + 2) * 68 + s] = kq.z;
            smem[K_OFF + (h4 + 3) * 68 + s] = kq.w;
            *(float4*)&smem[V_OFF + s * 36 + h4] = vg[idx4];
        }
        __syncthreads();

        // Phase A: 2x4 score tile; per kk: 1 b64 (q pair) + 1 b128 (k quad).
        float sc[2][4] = {};
        #pragma unroll 8
        for (int kk = 0; kk < 32; ++kk) {
            const float2 qv = *(const float2*)&smem[Q_OFF + kk * 36 + ty * 2];
            const float4 kv = *(const float4*)&smem[K_OFF + kk * 68 + tx * 4];
            sc[0][0] += qv.x * kv.x; sc[0][1] += qv.x * kv.y;
            sc[0][2] += qv.x * kv.z; sc[0][3] += qv.x * kv.w;
            sc[1][0] += qv.y * kv.x; sc[1][1] += qv.y * kv.y;
            sc[1][2] += qv.y * kv.z; sc[1][3] += qv.y * kv.w;
        }
        #pragma unroll
        for (int u = 0; u < 2; ++u)
            #pragma unroll
            for (int vv = 0; vv < 4; ++vv) {
                float e = __expf(sc[u][vv]);
                int sg = base + tx * 4 + vv;
                if (sg < 300) ssum[0][u] += e;
                else if (sg < 550) ssum[1][u] += e;
                else ssum[2][u] += e;
                smem[E_OFF + (tx * 4 + vv) * 36 + ty * 2 + u] = e;  // e_sT[s][t]
            }
        __syncthreads();

        // Phase B: wave wv covers ss in [wv*16, wv*16+16); uniform seg bounds.
        int e0 = min(max(300 - base, 0), 64);
        int e1 = min(max(550 - base, 0), 64);
        int lo = wv * 16, hi = lo + 16;
        for (int ss = lo, z = min(hi, e0); ss < z; ++ss) PV4(0)
        for (int ss = max(lo, e0), z = min(hi, e1); ss < z; ++ss) PV4(1)
        for (int ss = max(lo, e1); ss < hi; ++ss) PV4(2)
    }

    // Reduce ssum across tx (Phase A layout) -> S_s[t][seg].
    #pragma unroll
    for (int sg = 0; sg < 3; ++sg)
        #pragma unroll
        for (int u = 0; u < 2; ++u) {
            float v = ssum[sg][u];
            v += __shfl_down(v, 8, 16);
            v += __shfl_down(v, 4, 16);
            v += __shfl_down(v, 2, 16);
            v += __shfl_down(v, 1, 16);
            if (tx == 0) smem[S_OFF + (ty * 2 + u) * 3 + sg] = v;
        }
    __syncthreads();   // all Phase B done -> staging region dead; S_s visible

    // Cross-wave pacc reduction via red4 (aliased), one seg at a time.
    int tt = tid >> 3, q4 = tid & 7;       // epilogue layout: t-row, hd-quad
    float Pv[3][4];
    #pragma unroll
    for (int sg = 0; sg < 3; ++sg) {
        #pragma unroll
        for (int u = 0; u < 4; ++u)
            #pragma unroll
            for (int j = 0; j < 4; ++j)
                smem[R_OFF + wv * 1152 + (tq * 4 + u) * 36 + hq * 4 + j] =
                    pacc[sg][u][j];
        __syncthreads();
        float s0 = 0.f, s1 = 0.f, s2 = 0.f, s3 = 0.f;
        #pragma unroll
        for (int w = 0; w < 4; ++w) {
            const float4 r = *(const float4*)&smem[R_OFF + w * 1152 + tt * 36 + q4 * 4];
            s0 += r.x; s1 += r.y; s2 += r.z; s3 += r.w;
        }
        Pv[sg][0] = s0; Pv[sg][1] = s1; Pv[sg][2] = s2; Pv[sg][3] = s3;
        __syncthreads();
    }

    // Epilogue: 7 branch outputs, bf16 hi+lo, FRAGMENT-MAJOR addresses.
    int t_glob = t0 + tt;
    int g = (t_glob < 300) ? 0 : (t_glob < 550 ? 1 : 2);
    float S0 = smem[S_OFF + tt * 3 + 0];
    float S1 = smem[S_OFF + tt * 3 + 1];
    float S2 = smem[S_OFF + tt * 3 + 2];
    int b = bh >> 3, h = bh & 7;
    int row = t_glob * B + b;
    int lslot = (row & 15) + ((q4 >> 1) << 4);
    int j0 = (q4 & 1) * 4;
    // addr(i) = (((row>>4)*56 + i*8 + h)*64 + lslot)*8 + j0
    size_t fbase = (((size_t)(row >> 4) * 56 + h) * 64 + lslot) * 8 + j0;
    const int masks[7] = {7, 3, 5, 6, 1, 2, 4};  // LAV,LA,LV,AV,L,A,V
    #pragma unroll
    for (int i = 0; i < 7; ++i) {
        int m = masks[i];
        float n0 = 0.f, n1 = 0.f, n2 = 0.f, n3 = 0.f, den = 0.f;
        if (m & 1) { n0 += Pv[0][0]; n1 += Pv[0][1]; n2 += Pv[0][2]; n3 += Pv[0][3]; den += S0; }
        if (m & 2) { n0 += Pv[1][0]; n1 += Pv[1][1]; n2 += Pv[1][2]; n3 += Pv[1][3]; den += S1; }
        if (m & 4) { n0 += Pv[2][0]; n1 += Pv[2][1]; n2 += Pv[2][2]; n3 += Pv[2][3]; den += S2; }
        float r = 1.f / den;
        int live = (m >> g) & 1;
        float o[4];
        o[0] = live ? n0 * r : 0.f;
        o[1] = live ? n1 * r : 0.f;
        o[2] = live ? n2 * r : 0.f;
        o[3] = live ? n3 * r : 0.f;
        ushort4 hi4, lo4;
        unsigned short* hp = (unsigned short*)&hi4;
        unsigned short* lp = (unsigned short*)&lo4;
        #pragma unroll
        for (int j = 0; j < 4; ++j) {
            unsigned short hu = f2bf_u(o[j]);
            hp[j] = hu;
            lp[j] = f2bf_u(o[j] - bfu2f(hu));
        }
        size_t addr = fbase + (size_t)i * (8 * 64 * 8);   // i*8 kblks * 64 lanes * 8
        *(ushort4*)&Ohi[addr] = hi4;
        *(ushort4*)&Olo[addr] = lo4;
    }
}

// ---------------------------------------------------------------------------
// Weight combination: D_i = (final_w @ G_i @ out_w[i])^T stacked as (1792,256).
// ---------------------------------------------------------------------------
__device__ __forceinline__ float gsum_load(int i, int r2, int r,
                                           const void* sl, const void* sa,
                                           const void* sv, int f32)
{
    size_t base = (size_t)r2 * 1024;
    switch (i) {
        case 0: return ldu(sl, base + r, f32) + ldu(sa, base + r, f32) + ldu(sv, base + r, f32);
        case 1: return ldu(sl, base + 256 + r, f32) + ldu(sa, base + 256 + r, f32);
        case 2: return ldu(sl, base + 512 + r, f32) + ldu(sv, base + 256 + r, f32);
        case 3: return ldu(sa, base + 512 + r, f32) + ldu(sv, base + 512 + r, f32);
        case 4: return ldu(sl, base + 768 + r, f32);
        case 5: return ldu(sa, base + 768 + r, f32);
        default: return ldu(sv, base + 768 + r, f32);
    }
}

// Mtmp_i = G_i @ out_w[i]    (proven round-2)
__global__ __launch_bounds__(256) void wcomb1_kernel(
    const void* sl, const void* sa, const void* sv, const void* outw,
    const int* __restrict__ flag, float* __restrict__ Mtmp)
{
    int f32 = *flag;
    int bid = blockIdx.x;
    int i = bid >> 8, r2 = bid & 255;
    int c = threadIdx.x;
    __shared__ float g[256];
    g[c] = gsum_load(i, r2, c, sl, sa, sv, f32);
    __syncthreads();
    float acc = 0.f;
    for (int r = 0; r < 256; ++r)
        acc += g[r] * ldu(outw, (size_t)i * 65536 + r * 256 + c, f32);
    Mtmp[(size_t)i * 65536 + r2 * 256 + c] = acc;
}

// DT hi/lo in FRAGMENT-MAJOR layout: "row" = output col e, k = i*256+c.
__global__ __launch_bounds__(256) void wcomb2_gemm_kernel(
    const float* __restrict__ Mtmp, const void* finalw,
    const int* __restrict__ flag,
    unsigned short* __restrict__ DThi, unsigned short* __restrict__ DTlo)
{
    int f32 = *flag;
    int bx = blockIdx.x;   // col tile 0..3 (e)
    int by = blockIdx.y;   // row tile 0..3 (c)
    int i  = blockIdx.z;   // branch 0..6
    int tid = threadIdx.x;
    int tx = tid & 15, ty = tid >> 4;
    int colbase = bx * 64, rowbase = by * 64;
    __shared__ float As[64][33];   // Mtmp^T [c][j]
    __shared__ float Bs[32][65];   // finalw^T [j][e]
    float acc[4][4] = {};

    for (int kb = 0; kb < 8; ++kb) {
        __syncthreads();
        #pragma unroll
        for (int l = 0; l < 8; ++l) {
            int idx = l * 256 + tid;
            int r = idx & 63, kk = idx >> 6;      // r contiguous -> coalesced
            As[r][kk] = Mtmp[(size_t)i * 65536 + (kb * 32 + kk) * 256 + rowbase + r];
            int n = idx >> 5, k2 = idx & 31;      // k2 contiguous -> coalesced
            Bs[k2][n] = ldu(finalw, (size_t)(colbase + n) * 256 + kb * 32 + k2, f32);
        }
        __syncthreads();
        #pragma unroll 8
        for (int kk = 0; kk < 32; ++kk) {
            float av[4], bv[4];
            #pragma unroll
            for (int u = 0; u < 4; ++u) av[u] = As[ty * 4 + u][kk];
            #pragma unroll
            for (int v = 0; v < 4; ++v) bv[v] = Bs[kk][tx * 4 + v];
            #pragma unroll
            for (int u = 0; u < 4; ++u)
                #pragma unroll
                for (int v = 0; v < 4; ++v)
                    acc[u][v] += av[u] * bv[v];
        }
    }
    #pragma unroll
    for (int u = 0; u < 4; ++u)
        #pragma unroll
        for (int v = 0; v < 4; ++v) {
            int c = rowbase + ty * 4 + u, e = colbase + tx * 4 + v;
            float a = acc[u][v];
            unsigned short hu = f2bf_u(a);
            // fragment-major: rb=e>>4, kblk=i*8+(c>>5), lane=(e&15)|(((c>>3)&3)<<4), j=c&7
            size_t fidx = (((size_t)(e >> 4) * 56 + i * 8 + (c >> 5)) * 64
                           + (e & 15) + (((c >> 3) & 3) << 4)) * 8 + (c & 7);
            DThi[fidx] = hu;
            DTlo[fidx] = f2bf_u(a - bfu2f(hu));
        }
}

// ---------------------------------------------------------------------------
// Bias path (proven round-5). c0 ALIASES Mtmp (dead after wcomb2).
// ws footprint unchanged from proven layout — do NOT grow it.
// ---------------------------------------------------------------------------
__global__ __launch_bounds__(256) void bias1_kernel(
    const void* sl, const void* sa, const void* sv, const void* outb,
    const void* slb, const void* sab, const void* svb,
    const int* __restrict__ flag, float* __restrict__ c0)
{
    int f32 = *flag;
    int r2 = blockIdx.x, m = threadIdx.x;
    __shared__ float red[256];
    float acc = 0.f;
    #pragma unroll
    for (int i = 0; i < 7; ++i)
        acc += ldu(outb, i * 256 + m, f32) * gsum_load(i, r2, m, sl, sa, sv, f32);
    red[m] = acc;
    __syncthreads();
    for (int s = 128; s > 0; s >>= 1) {
        if (m < s) red[m] += red[m + s];
        __syncthreads();
    }
    if (m == 0)
        c0[r2] = red[0] + ldu(slb, r2, f32) + ldu(sab, r2, f32) + ldu(svb, r2, f32);
}

__global__ __launch_bounds__(256) void bias2_kernel(
    const float* __restrict__ c0, const void* finalw, const void* finalb,
    const int* __restrict__ flag, float* __restrict__ d0)
{
    int f32 = *flag;
    int e = blockIdx.x, r = threadIdx.x;
    __shared__ float red[256];
    red[r] = c0[r] * ldu(finalw, (size_t)e * 256 + r, f32);
    __syncthreads();
    for (int s = 128; s > 0; s >>= 1) {
        if (r < s) red[r] += red[r + s];
        __syncthreads();
    }
    if (r == 0)
        d0[e] = red[0] + ldu(finalb, e, f32);
}

// ---------------------------------------------------------------------------
// Kernel 4 (MFMA, round-13 fragment-major loads): result = O @ Dstack + d0.
// Per (rowblk,kblk) a wave loads base+lane*8 — 1KB contiguous.
// ---------------------------------------------------------------------------
__global__ __launch_bounds__(256) void final_gemm_mfma_kernel(
    const unsigned short* __restrict__ Ohi, const unsigned short* __restrict__ Olo,
    const unsigned short* __restrict__ DThi, const unsigned short* __restrict__ DTlo,
    const float* __restrict__ d0, const int* __restrict__ flag,
    void* __restrict__ outv)
{
    int f32 = *flag;
    int bx = blockIdx.x;          // col group 0..3 (64 cols)
    int by = blockIdx.y;          // row group 0..191 (16 rows)
    int w  = threadIdx.x >> 6;    // wave 0..3
    int lane = threadIdx.x & 63;
    int m = lane & 15, quad = lane >> 4;
    int R0 = by * 16, C0 = bx * 64 + w * 16;

    int t0 = R0 >> 2, t1 = (R0 + 15) >> 2;
    int g0 = (t0 < 300) ? 0 : (t0 < 550 ? 1 : 2);
    int g1 = (t1 < 300) ? 0 : (t1 < 550 ? 1 : 2);
    int activeset = (1 << g0) | (1 << g1);
    const int masks[7] = {7, 3, 5, 6, 1, 2, 4};

    // fragment-major bases: buf + rb*56*512 + lane*8; per (i,kb) offset (i*8+kb)*512
    const unsigned short* Abase_h = Ohi + (size_t)by * 56 * 512 + lane * 8;
    const unsigned short* Abase_l = Olo + (size_t)by * 56 * 512 + lane * 8;
    const unsigned short* Bbase_h = DThi + (size_t)(bx * 4 + w) * 56 * 512 + lane * 8;
    const unsigned short* Bbase_l = DTlo + (size_t)(bx * 4 + w) * 56 * 512 + lane * 8;

    f32x4 acc = {};
    for (int i = 0; i < 7; ++i) {
        if (!(masks[i] & activeset)) continue;   // O block exactly zero
        #pragma unroll
        for (int kb = 0; kb < 8; ++kb) {
            size_t off = (size_t)(i * 8 + kb) * 512;
            bf16x8 ah = *(const bf16x8*)(Abase_h + off);
            bf16x8 al = *(const bf16x8*)(Abase_l + off);
            bf16x8 bh = *(const bf16x8*)(Bbase_h + off);
            bf16x8 bl = *(const bf16x8*)(Bbase_l + off);
            acc = __builtin_amdgcn_mfma_f32_16x16x32_bf16(ah, bh, acc, 0, 0, 0);
            acc = __builtin_amdgcn_mfma_f32_16x16x32_bf16(ah, bl, acc, 0, 0, 0);
            acc = __builtin_amdgcn_mfma_f32_16x16x32_bf16(al, bh, acc, 0, 0, 0);
        }
    }
    float dv = d0[C0 + m];
    #pragma unroll
    for (int r = 0; r < 4; ++r) {
        int row = R0 + quad * 4 + r;
        int col = C0 + m;
        float val = acc[r] + dv;
        if (f32) ((float*)outv)[(size_t)row * 256 + col] = val;
        else ((__hip_bfloat16*)outv)[(size_t)row * 256 + col] = __float2bfloat16(val);
    }
}

// ---------------------------------------------------------------------------
extern "C" void kernel_launch(void* const* d_in, const int* in_sizes, int n_in,
                              void* d_out, int out_size, void* d_ws, size_t ws_size,
                              hipStream_t stream) {
    const void* query     = d_in[0];
    const void* key       = d_in[1];
    const void* value     = d_in[2];
    const void* in_proj_w = d_in[3];
    const void* in_proj_b = d_in[4];
    const void* out_w     = d_in[5];
    const void* out_b     = d_in[6];
    const void* s_l_w     = d_in[7];
    const void* s_l_b     = d_in[8];
    const void* s_a_w     = d_in[9];
    const void* s_a_b     = d_in[10];
    const void* s_v_w     = d_in[11];
    const void* s_v_b     = d_in[12];
    const void* final_w   = d_in[13];
    const void* final_b   = d_in[14];

    float* ws     = (float*)d_ws;
    float* qws    = ws;                 //   786432 f
    float* kws    = ws + 786432;        //   786432 f
    float* vws    = ws + 1572864;       //   786432 f
    // O region: fragment-major bf16 hi+lo planes (192*56*64*8 = 5505024 each):
    unsigned short* Ohi = (unsigned short*)(ws + 2359296);   // 5505024 bf16
    unsigned short* Olo = (unsigned short*)(ws + 5111808);   // 5505024 bf16
    float* Mtmp   = ws + 7864320;       //   458752 f
    // DT region: fragment-major bf16 hi+lo (16*56*64*8 = 458752 each):
    unsigned short* DThi = (unsigned short*)(ws + 8323072);  // 458752 bf16
    unsigned short* DTlo = (unsigned short*)(ws + 8552448);  // 458752 bf16
    float* d0     = ws + 8781824;       //      256 f
    int*   flag   = (int*)(ws + 8782080);  // 1 int — proven footprint HIGH-WATER
    float* c0     = Mtmp;               // ALIAS: Mtmp dead after wcomb2

    detect_kernel<<<1, 64, 0, stream>>>((const unsigned short*)query, flag);
    qkv_gemm_kernel<<<dim3(12, 48), 256, 0, stream>>>(query, key, value,
                                                      in_proj_w, in_proj_b, flag,
                                                      qws, kws, vws);
    wcomb1_kernel<<<7 * 256, 256, 0, stream>>>(s_l_w, s_a_w, s_v_w, out_w, flag, Mtmp);
    attn_tiled_kernel<<<dim3(24, 32), 256, 0, stream>>>(qws, kws, vws, Ohi, Olo);
    wcomb2_gemm_kernel<<<dim3(4, 4, 7), 256, 0, stream>>>(Mtmp, final_w, flag,
                                                          DThi, DTlo);
    bias1_kernel<<<256, 256, 0, stream>>>(s_l_w, s_a_w, s_v_w, out_b,
                                          s_l_b, s_a_b, s_v_b, flag, c0);
    bias2_kernel<<<256, 256, 0, stream>>>(c0, final_w, final_b, flag, d0);
    final_gemm_mfma_kernel<<<dim3(4, 192), 256, 0, stream>>>(Ohi, Olo, DThi, DTlo,
                                                             d0, flag, d_out);
}

// Round 14
// 249.571 us; speedup vs baseline: 1.6182x; 1.1158x over previous
//
#include <hip/hip_runtime.h>
#include <hip/hip_bf16.h>

#define E 256
#define H 8
#define HD 32
#define T 768
#define B 4
#define BH 32
// segments: L=[0,300), A=[300,550), V=[550,768)

typedef __attribute__((ext_vector_type(8))) short bf16x8;
typedef __attribute__((ext_vector_type(4))) float f32x4;

__device__ __forceinline__ float b2f(__hip_bfloat16 x) { return __bfloat162float(x); }

__device__ __forceinline__ unsigned short f2bf_u(float x) {
    __hip_bfloat16 h = __float2bfloat16(x);
    return *(unsigned short*)&h;
}
__device__ __forceinline__ float bfu2f(unsigned short u) {
    return __uint_as_float(((unsigned int)u) << 16);
}

// split fp32[8] -> bf16 hi + lo fragments
__device__ __forceinline__ void f8_split(const float* v, bf16x8& h, bf16x8& l) {
    #pragma unroll
    for (int e = 0; e < 8; ++e) {
        unsigned short hu = f2bf_u(v[e]);
        h[e] = (short)hu;
        l[e] = (short)f2bf_u(v[e] - bfu2f(hu));
    }
}

#define MFMA3(ACC, AH, AL, BH_, BL_)                                         \
    ACC = __builtin_amdgcn_mfma_f32_16x16x32_bf16(AH, BH_, ACC, 0, 0, 0);    \
    ACC = __builtin_amdgcn_mfma_f32_16x16x32_bf16(AH, BL_, ACC, 0, 0, 0);    \
    ACC = __builtin_amdgcn_mfma_f32_16x16x32_bf16(AL, BH_, ACC, 0, 0, 0);

// dtype-agnostic scalar load: f32 ? float : bf16
__device__ __forceinline__ float ldu(const void* p, size_t i, int f32) {
    if (f32) return ((const float*)p)[i];
    return b2f(((const __hip_bfloat16*)p)[i]);
}

// ---------------------------------------------------------------------------
// Kernel 0: input dtype detection (fp32 read as bf16 -> garbage exponents).
// ---------------------------------------------------------------------------
__global__ void detect_kernel(const unsigned short* __restrict__ q,
                              int* __restrict__ flag) {
    if (threadIdx.x == 0 && blockIdx.x == 0) {
        int f32 = 0;
        for (int i = 0; i < 256; ++i) {
            unsigned int bits = ((unsigned int)q[i]) << 16;
            float v = __uint_as_float(bits);
            if (!(v == v) || fabsf(v) > 1e4f) f32 = 1;
        }
        *flag = f32;
    }
}

// ---------------------------------------------------------------------------
// Kernel 1: QKV projection (proven round-12 LDS-vectorized retile).
// ---------------------------------------------------------------------------
__global__ __launch_bounds__(256) void qkv_gemm_kernel(
    const void* query, const void* key, const void* value,
    const void* w, const void* bias, const int* __restrict__ flag,
    float* __restrict__ qws, float* __restrict__ kws, float* __restrict__ vws)
{
    int f32 = *flag;
    int bx = blockIdx.x;              // 0..11 col tiles
    int by = blockIdx.y;              // 0..47 row tiles
    int sec = bx >> 2;                // 0=q, 1=k, 2=v
    const void* X = (sec == 0) ? query : (sec == 1) ? key : value;
    int colbase = bx * 64;
    int rowbase = by * 64;
    int tid = threadIdx.x;
    int tx = tid & 15, ty = tid >> 4;
    __shared__ __align__(16) float AsT[32][68];   // [kk][row]
    __shared__ __align__(16) float Bs[32][68];    // [kk][col]
    float acc[4][4] = {};

    for (int kb = 0; kb < 8; ++kb) {
        __syncthreads();
        if (f32) {
            const float4* Xg = (const float4*)((const float*)X +
                                (size_t)rowbase * 256 + kb * 32);
            const float4* Wg = (const float4*)((const float*)w +
                                (size_t)colbase * 256 + kb * 32);
            #pragma unroll
            for (int l = 0; l < 2; ++l) {
                int idx4 = l * 256 + tid;
                int r = idx4 >> 3, kq = idx4 & 7;
                float4 xv = Xg[(size_t)r * 64 + kq];
                AsT[kq * 4 + 0][r] = xv.x;
                AsT[kq * 4 + 1][r] = xv.y;
                AsT[kq * 4 + 2][r] = xv.z;
                AsT[kq * 4 + 3][r] = xv.w;
                float4 wv = Wg[(size_t)r * 64 + kq];
                Bs[kq * 4 + 0][r] = wv.x;
                Bs[kq * 4 + 1][r] = wv.y;
                Bs[kq * 4 + 2][r] = wv.z;
                Bs[kq * 4 + 3][r] = wv.w;
            }
        } else {
            #pragma unroll
            for (int l = 0; l < 2; ++l) {
                int idx4 = l * 256 + tid;
                int r = idx4 >> 3, kq = idx4 & 7;
                #pragma unroll
                for (int j = 0; j < 4; ++j) {
                    AsT[kq * 4 + j][r] =
                        ldu(X, (size_t)(rowbase + r) * 256 + kb * 32 + kq * 4 + j, 0);
                    Bs[kq * 4 + j][r] =
                        ldu(w, (size_t)(colbase + r) * 256 + kb * 32 + kq * 4 + j, 0);
                }
            }
        }
        __syncthreads();
        #pragma unroll 8
        for (int kk = 0; kk < 32; ++kk) {
            const float4 av = *(const float4*)&AsT[kk][ty * 4];
            const float4 bv = *(const float4*)&Bs[kk][tx * 4];
            acc[0][0] += av.x * bv.x; acc[0][1] += av.x * bv.y;
            acc[0][2] += av.x * bv.z; acc[0][3] += av.x * bv.w;
            acc[1][0] += av.y * bv.x; acc[1][1] += av.y * bv.y;
            acc[1][2] += av.y * bv.z; acc[1][3] += av.y * bv.w;
            acc[2][0] += av.z * bv.x; acc[2][1] += av.z * bv.y;
            acc[2][2] += av.z * bv.z; acc[2][3] += av.z * bv.w;
            acc[3][0] += av.w * bv.x; acc[3][1] += av.w * bv.y;
            acc[3][2] += av.w * bv.z; acc[3][3] += av.w * bv.w;
        }
    }
    float* dst = (sec == 0) ? qws : (sec == 1) ? kws : vws;
    #pragma unroll
    for (int u = 0; u < 4; ++u)
        #pragma unroll
        for (int v = 0; v < 4; ++v) {
            int r = rowbase + ty * 4 + u;          // t*B + b
            int cg = colbase + tx * 4 + v;         // 0..767
            float val = acc[u][v] + ldu(bias, cg, f32);
            if (sec == 0) val *= 0.17677669529663687f;  // HD^-0.5
            int e_local = cg & 255;
            int h = e_local >> 5, hd = e_local & 31;
            int t = r >> 2, b = r & 3;
            dst[((size_t)((b * H + h) * T + t)) * HD + hd] = val;
        }
}

// ---------------------------------------------------------------------------
// Kernel 2 (NEW round-14): MFMA attention. Block = (32-row t-tile, bh).
// Both matmuls on 16x16x32 bf16 MFMA with hi+lo split (r11-proven convention:
// D[row][col] = sum_k A[row][k]*B[col][k]; A-frag lane m=lane&15 holds
// A[m][quad*8+j]; C/D: col=lane&15, row=quad*4+r).
// Wave w: score tiles (tb=w&1, sb={2*(w>>1), +1}); P tile (tb, hdb=w>>1).
// e packed (hi | lo<<16) into A-fragment-major LDS. Segment boundaries inside
// a k-step handled by element-masked dual MFMAs (only 2 such k-steps).
// ---------------------------------------------------------------------------
__global__ __launch_bounds__(256) void attn_mfma_kernel(
    const float* __restrict__ qws, const float* __restrict__ kws,
    const float* __restrict__ vws,
    unsigned short* __restrict__ Ohi, unsigned short* __restrict__ Olo)
{
    int tile = blockIdx.x;       // 0..23
    int bh   = blockIdx.y;       // 0..31
    int t0 = tile * 32;
    int tid = threadIdx.x;
    int w = tid >> 6, lane = tid & 63;
    int m = lane & 15, quad = lane >> 4;
    int tb = w & 1, hdb = w >> 1;

    __shared__ __align__(16) unsigned short KFH[2048], KFL[2048];  // [4sb][64][8]
    __shared__ __align__(16) unsigned short VFH[2048], VFL[2048];  // [2hdb][2ks][64][8]
    __shared__ __align__(16) unsigned int   EPK[2048];             // [2tb][2ks][64][8]
    __shared__ float SP[4][16][3];
    __shared__ __align__(16) float PL[3 * 32 * 36];

    // q fragment (chunk-invariant, registers): A[m=t16][k=hd]
    bf16x8 aqh, aql;
    {
        const float* qr = qws + ((size_t)bh * T + t0 + tb * 16 + m) * HD + quad * 8;
        float qv[8];
        *(float4*)&qv[0] = *(const float4*)qr;
        *(float4*)&qv[4] = *(const float4*)(qr + 4);
        f8_split(qv, aqh, aql);
    }

    f32x4 acc0 = {}, acc1 = {}, acc2 = {};
    float ss0[4] = {}, ss1[4] = {}, ss2[4] = {};

    const float* kbase = kws + (size_t)bh * T * HD;
    const float* vbase = vws + (size_t)bh * T * HD;

    for (int ch = 0; ch < 12; ++ch) {
        int base = ch * 64;
        __syncthreads();
        // --- stage k fragments: slot (sb=tid>>6, lane) ---
        {
            int sb = tid >> 6, ln = tid & 63, km = ln & 15, kq = ln >> 4;
            const float* kr = kbase + (size_t)(base + sb * 16 + km) * HD + kq * 8;
            float kv[8];
            *(float4*)&kv[0] = *(const float4*)kr;
            *(float4*)&kv[4] = *(const float4*)(kr + 4);
            bf16x8 h, l;
            f8_split(kv, h, l);
            *(bf16x8*)&KFH[(sb * 64 + ln) * 8] = h;
            *(bf16x8*)&KFL[(sb * 64 + ln) * 8] = l;
        }
        // --- stage v fragments (transposed): slot (hdb=tid>>7, ks, lane) ---
        {
            int vh = tid >> 7, vks = (tid >> 6) & 1, vln = tid & 63;
            int vm = vln & 15, vq = vln >> 4;
            const float* vr = vbase + (size_t)(base + vks * 32 + vq * 8) * HD
                              + vh * 16 + vm;
            float vv[8];
            #pragma unroll
            for (int j = 0; j < 8; ++j) vv[j] = vr[(size_t)j * HD];
            bf16x8 h, l;
            f8_split(vv, h, l);
            *(bf16x8*)&VFH[((vh * 2 + vks) * 64 + vln) * 8] = h;
            *(bf16x8*)&VFL[((vh * 2 + vks) * 64 + vln) * 8] = l;
        }
        __syncthreads();

        // --- scores + exp + e_frag writes ---
        #pragma unroll
        for (int sbi = 0; sbi < 2; ++sbi) {
            int sb = (w >> 1) * 2 + sbi;
            bf16x8 bkh = *(const bf16x8*)&KFH[(sb * 64 + lane) * 8];
            bf16x8 bkl = *(const bf16x8*)&KFL[(sb * 64 + lane) * 8];
            f32x4 d = {};
            MFMA3(d, aqh, aql, bkh, bkl)
            int s64 = sb * 16 + m;           // s within chunk (C/D col)
            int sglob = base + s64;
            int ksw = s64 >> 5, qp = (s64 >> 3) & 3, jp = m & 7;
            unsigned int* eb = &EPK[(tb * 2 + ksw) * 512 + jp];
            #pragma unroll
            for (int r = 0; r < 4; ++r) {
                float e = __expf(d[r]);
                if (sglob < 300) ss0[r] += e;
                else if (sglob < 550) ss1[r] += e;
                else ss2[r] += e;
                unsigned short hu = f2bf_u(e);
                unsigned short lu = f2bf_u(e - bfu2f(hu));
                eb[((quad * 4 + r) + 16 * qp) * 8] =
                    (unsigned int)hu | ((unsigned int)lu << 16);
            }
        }
        __syncthreads();

        // --- PV: wave's (tb, hdb) tile, 2 k-steps ---
        #pragma unroll
        for (int ks = 0; ks < 2; ++ks) {
            const unsigned int* ep = &EPK[((tb * 2 + ks) * 64 + lane) * 8];
            uint4 p0 = *(const uint4*)ep;
            uint4 p1 = *(const uint4*)(ep + 4);
            bf16x8 aeh, ael;
            aeh[0] = (short)(p0.x & 0xffff); ael[0] = (short)(p0.x >> 16);
            aeh[1] = (short)(p0.y & 0xffff); ael[1] = (short)(p0.y >> 16);
            aeh[2] = (short)(p0.z & 0xffff); ael[2] = (short)(p0.z >> 16);
            aeh[3] = (short)(p0.w & 0xffff); ael[3] = (short)(p0.w >> 16);
            aeh[4] = (short)(p1.x & 0xffff); ael[4] = (short)(p1.x >> 16);
            aeh[5] = (short)(p1.y & 0xffff); ael[5] = (short)(p1.y >> 16);
            aeh[6] = (short)(p1.z & 0xffff); ael[6] = (short)(p1.z >> 16);
            aeh[7] = (short)(p1.w & 0xffff); ael[7] = (short)(p1.w >> 16);
            bf16x8 bvh = *(const bf16x8*)&VFH[((hdb * 2 + ks) * 64 + lane) * 8];
            bf16x8 bvl = *(const bf16x8*)&VFL[((hdb * 2 + ks) * 64 + lane) * 8];
            int s_lo = base + ks * 32;
            if (s_lo + 32 <= 300) { MFMA3(acc0, aeh, ael, bvh, bvl) }
            else if (s_lo >= 300 && s_lo + 32 <= 550) { MFMA3(acc1, aeh, ael, bvh, bvl) }
            else if (s_lo >= 550) { MFMA3(acc2, aeh, ael, bvh, bvl) }
            else {
                int bnd = (s_lo < 300) ? 300 : 550;
                bf16x8 eha = aeh, ela = ael, ehb = aeh, elb = ael;
                #pragma unroll
                for (int j = 0; j < 8; ++j) {
                    int s = s_lo + quad * 8 + j;
                    if (s < bnd) { ehb[j] = 0; elb[j] = 0; }
                    else         { eha[j] = 0; ela[j] = 0; }
                }
                if (s_lo < 300) { MFMA3(acc0, eha, ela, bvh, bvl)
                                  MFMA3(acc1, ehb, elb, bvh, bvl) }
                else            { MFMA3(acc1, eha, ela, bvh, bvl)
                                  MFMA3(acc2, ehb, elb, bvh, bvl) }
            }
        }
    }

    // S partials: reduce over the 16 s-lanes (width-16 shuffle), SP[w][t16][seg].
    #pragma unroll
    for (int sg = 0; sg < 3; ++sg)
        #pragma unroll
        for (int r = 0; r < 4; ++r) {
            float v = (sg == 0) ? ss0[r] : (sg == 1) ? ss1[r] : ss2[r];
            v += __shfl_down(v, 8, 16);
            v += __shfl_down(v, 4, 16);
            v += __shfl_down(v, 2, 16);
            v += __shfl_down(v, 1, 16);
            if (m == 0) SP[w][quad * 4 + r][sg] = v;
        }
    // P (C/D layout) -> PL[seg][t32][hd32] (stride 36)
    #pragma unroll
    for (int r = 0; r < 4; ++r) {
        int t32 = tb * 16 + quad * 4 + r;
        int hd = hdb * 16 + m;
        PL[0 * 1152 + t32 * 36 + hd] = acc0[r];
        PL[1 * 1152 + t32 * 36 + hd] = acc1[r];
        PL[2 * 1152 + t32 * 36 + hd] = acc2[r];
    }
    __syncthreads();

    // Epilogue (r13-proven): tt=t-row, q4=hd-quad; fragment-major O store.
    int tt = tid >> 3, q4 = tid & 7;
    float Pv[3][4];
    #pragma unroll
    for (int sg = 0; sg < 3; ++sg) {
        const float4 p = *(const float4*)&PL[sg * 1152 + tt * 36 + q4 * 4];
        Pv[sg][0] = p.x; Pv[sg][1] = p.y; Pv[sg][2] = p.z; Pv[sg][3] = p.w;
    }
    int tbe = tt >> 4, t16 = tt & 15;
    float S0 = SP[tbe][t16][0] + SP[tbe + 2][t16][0];
    float S1 = SP[tbe][t16][1] + SP[tbe + 2][t16][1];
    float S2 = SP[tbe][t16][2] + SP[tbe + 2][t16][2];

    int t_glob = t0 + tt;
    int g = (t_glob < 300) ? 0 : (t_glob < 550 ? 1 : 2);
    int b_ = bh >> 3, h_ = bh & 7;
    int row = t_glob * B + b_;
    int lslot = (row & 15) + ((q4 >> 1) << 4);
    int j0 = (q4 & 1) * 4;
    size_t fbase = (((size_t)(row >> 4) * 56 + h_) * 64 + lslot) * 8 + j0;
    const int masks[7] = {7, 3, 5, 6, 1, 2, 4};  // LAV,LA,LV,AV,L,A,V
    #pragma unroll
    for (int i = 0; i < 7; ++i) {
        int mm = masks[i];
        float n0 = 0.f, n1 = 0.f, n2 = 0.f, n3 = 0.f, den = 0.f;
        if (mm & 1) { n0 += Pv[0][0]; n1 += Pv[0][1]; n2 += Pv[0][2]; n3 += Pv[0][3]; den += S0; }
        if (mm & 2) { n0 += Pv[1][0]; n1 += Pv[1][1]; n2 += Pv[1][2]; n3 += Pv[1][3]; den += S1; }
        if (mm & 4) { n0 += Pv[2][0]; n1 += Pv[2][1]; n2 += Pv[2][2]; n3 += Pv[2][3]; den += S2; }
        float r = 1.f / den;
        int live = (mm >> g) & 1;
        float o[4];
        o[0] = live ? n0 * r : 0.f;
        o[1] = live ? n1 * r : 0.f;
        o[2] = live ? n2 * r : 0.f;
        o[3] = live ? n3 * r : 0.f;
        ushort4 hi4, lo4;
        unsigned short* hp = (unsigned short*)&hi4;
        unsigned short* lp = (unsigned short*)&lo4;
        #pragma unroll
        for (int j = 0; j < 4; ++j) {
            unsigned short hu = f2bf_u(o[j]);
            hp[j] = hu;
            lp[j] = f2bf_u(o[j] - bfu2f(hu));
        }
        size_t addr = fbase + (size_t)i * (8 * 64 * 8);
        *(ushort4*)&Ohi[addr] = hi4;
        *(ushort4*)&Olo[addr] = lo4;
    }
}

// ---------------------------------------------------------------------------
// Weight combination: D_i = (final_w @ G_i @ out_w[i])^T stacked as (1792,256).
// ---------------------------------------------------------------------------
__device__ __forceinline__ float gsum_load(int i, int r2, int r,
                                           const void* sl, const void* sa,
                                           const void* sv, int f32)
{
    size_t base = (size_t)r2 * 1024;
    switch (i) {
        case 0: return ldu(sl, base + r, f32) + ldu(sa, base + r, f32) + ldu(sv, base + r, f32);
        case 1: return ldu(sl, base + 256 + r, f32) + ldu(sa, base + 256 + r, f32);
        case 2: return ldu(sl, base + 512 + r, f32) + ldu(sv, base + 256 + r, f32);
        case 3: return ldu(sa, base + 512 + r, f32) + ldu(sv, base + 512 + r, f32);
        case 4: return ldu(sl, base + 768 + r, f32);
        case 5: return ldu(sa, base + 768 + r, f32);
        default: return ldu(sv, base + 768 + r, f32);
    }
}

// Mtmp_i = G_i @ out_w[i]    (proven round-2)
__global__ __launch_bounds__(256) void wcomb1_kernel(
    const void* sl, const void* sa, const void* sv, const void* outw,
    const int* __restrict__ flag, float* __restrict__ Mtmp)
{
    int f32 = *flag;
    int bid = blockIdx.x;
    int i = bid >> 8, r2 = bid & 255;
    int c = threadIdx.x;
    __shared__ float g[256];
    g[c] = gsum_load(i, r2, c, sl, sa, sv, f32);
    __syncthreads();
    float acc = 0.f;
    for (int r = 0; r < 256; ++r)
        acc += g[r] * ldu(outw, (size_t)i * 65536 + r * 256 + c, f32);
    Mtmp[(size_t)i * 65536 + r2 * 256 + c] = acc;
}

// DT hi/lo in FRAGMENT-MAJOR layout (proven round-13).
__global__ __launch_bounds__(256) void wcomb2_gemm_kernel(
    const float* __restrict__ Mtmp, const void* finalw,
    const int* __restrict__ flag,
    unsigned short* __restrict__ DThi, unsigned short* __restrict__ DTlo)
{
    int f32 = *flag;
    int bx = blockIdx.x;   // col tile 0..3 (e)
    int by = blockIdx.y;   // row tile 0..3 (c)
    int i  = blockIdx.z;   // branch 0..6
    int tid = threadIdx.x;
    int tx = tid & 15, ty = tid >> 4;
    int colbase = bx * 64, rowbase = by * 64;
    __shared__ float As[64][33];   // Mtmp^T [c][j]
    __shared__ float Bs[32][65];   // finalw^T [j][e]
    float acc[4][4] = {};

    for (int kb = 0; kb < 8; ++kb) {
        __syncthreads();
        #pragma unroll
        for (int l = 0; l < 8; ++l) {
            int idx = l * 256 + tid;
            int r = idx & 63, kk = idx >> 6;
            As[r][kk] = Mtmp[(size_t)i * 65536 + (kb * 32 + kk) * 256 + rowbase + r];
            int n = idx >> 5, k2 = idx & 31;
            Bs[k2][n] = ldu(finalw, (size_t)(colbase + n) * 256 + kb * 32 + k2, f32);
        }
        __syncthreads();
        #pragma unroll 8
        for (int kk = 0; kk < 32; ++kk) {
            float av[4], bv[4];
            #pragma unroll
            for (int u = 0; u < 4; ++u) av[u] = As[ty * 4 + u][kk];
            #pragma unroll
            for (int v = 0; v < 4; ++v) bv[v] = Bs[kk][tx * 4 + v];
            #pragma unroll
            for (int u = 0; u < 4; ++u)
                #pragma unroll
                for (int v = 0; v < 4; ++v)
                    acc[u][v] += av[u] * bv[v];
        }
    }
    #pragma unroll
    for (int u = 0; u < 4; ++u)
        #pragma unroll
        for (int v = 0; v < 4; ++v) {
            int c = rowbase + ty * 4 + u, e = colbase + tx * 4 + v;
            float a = acc[u][v];
            unsigned short hu = f2bf_u(a);
            size_t fidx = (((size_t)(e >> 4) * 56 + i * 8 + (c >> 5)) * 64
                           + (e & 15) + (((c >> 3) & 3) << 4)) * 8 + (c & 7);
            DThi[fidx] = hu;
            DTlo[fidx] = f2bf_u(a - bfu2f(hu));
        }
}

// ---------------------------------------------------------------------------
// Bias path (proven round-5). c0 ALIASES Mtmp (dead after wcomb2).
// ---------------------------------------------------------------------------
__global__ __launch_bounds__(256) void bias1_kernel(
    const void* sl, const void* sa, const void* sv, const void* outb,
    const void* slb, const void* sab, const void* svb,
    const int* __restrict__ flag, float* __restrict__ c0)
{
    int f32 = *flag;
    int r2 = blockIdx.x, m = threadIdx.x;
    __shared__ float red[256];
    float acc = 0.f;
    #pragma unroll
    for (int i = 0; i < 7; ++i)
        acc += ldu(outb, i * 256 + m, f32) * gsum_load(i, r2, m, sl, sa, sv, f32);
    red[m] = acc;
    __syncthreads();
    for (int s = 128; s > 0; s >>= 1) {
        if (m < s) red[m] += red[m + s];
        __syncthreads();
    }
    if (m == 0)
        c0[r2] = red[0] + ldu(slb, r2, f32) + ldu(sab, r2, f32) + ldu(svb, r2, f32);
}

__global__ __launch_bounds__(256) void bias2_kernel(
    const float* __restrict__ c0, const void* finalw, const void* finalb,
    const int* __restrict__ flag, float* __restrict__ d0)
{
    int f32 = *flag;
    int e = blockIdx.x, r = threadIdx.x;
    __shared__ float red[256];
    red[r] = c0[r] * ldu(finalw, (size_t)e * 256 + r, f32);
    __syncthreads();
    for (int s = 128; s > 0; s >>= 1) {
        if (r < s) red[r] += red[r + s];
        __syncthreads();
    }
    if (r == 0)
        d0[e] = red[0] + ldu(finalb, e, f32);
}

// ---------------------------------------------------------------------------
// Kernel 4 (proven round-13, MFMA + fragment-major): result = O@Dstack + d0.
// ---------------------------------------------------------------------------
__global__ __launch_bounds__(256) void final_gemm_mfma_kernel(
    const unsigned short* __restrict__ Ohi, const unsigned short* __restrict__ Olo,
    const unsigned short* __restrict__ DThi, const unsigned short* __restrict__ DTlo,
    const float* __restrict__ d0, const int* __restrict__ flag,
    void* __restrict__ outv)
{
    int f32 = *flag;
    int bx = blockIdx.x;          // col group 0..3 (64 cols)
    int by = blockIdx.y;          // row group 0..191 (16 rows)
    int w  = threadIdx.x >> 6;    // wave 0..3
    int lane = threadIdx.x & 63;
    int m = lane & 15, quad = lane >> 4;
    int R0 = by * 16, C0 = bx * 64 + w * 16;

    int t0 = R0 >> 2, t1 = (R0 + 15) >> 2;
    int g0 = (t0 < 300) ? 0 : (t0 < 550 ? 1 : 2);
    int g1 = (t1 < 300) ? 0 : (t1 < 550 ? 1 : 2);
    int activeset = (1 << g0) | (1 << g1);
    const int masks[7] = {7, 3, 5, 6, 1, 2, 4};

    const unsigned short* Abase_h = Ohi + (size_t)by * 56 * 512 + lane * 8;
    const unsigned short* Abase_l = Olo + (size_t)by * 56 * 512 + lane * 8;
    const unsigned short* Bbase_h = DThi + (size_t)(bx * 4 + w) * 56 * 512 + lane * 8;
    const unsigned short* Bbase_l = DTlo + (size_t)(bx * 4 + w) * 56 * 512 + lane * 8;

    f32x4 acc = {};
    for (int i = 0; i < 7; ++i) {
        if (!(masks[i] & activeset)) continue;
        #pragma unroll
        for (int kb = 0; kb < 8; ++kb) {
            size_t off = (size_t)(i * 8 + kb) * 512;
            bf16x8 ah = *(const bf16x8*)(Abase_h + off);
            bf16x8 al = *(const bf16x8*)(Abase_l + off);
            bf16x8 bh = *(const bf16x8*)(Bbase_h + off);
            bf16x8 bl = *(const bf16x8*)(Bbase_l + off);
            acc = __builtin_amdgcn_mfma_f32_16x16x32_bf16(ah, bh, acc, 0, 0, 0);
            acc = __builtin_amdgcn_mfma_f32_16x16x32_bf16(ah, bl, acc, 0, 0, 0);
            acc = __builtin_amdgcn_mfma_f32_16x16x32_bf16(al, bh, acc, 0, 0, 0);
        }
    }
    float dv = d0[C0 + m];
    #pragma unroll
    for (int r = 0; r < 4; ++r) {
        int row = R0 + quad * 4 + r;
        int col = C0 + m;
        float val = acc[r] + dv;
        if (f32) ((float*)outv)[(size_t)row * 256 + col] = val;
        else ((__hip_bfloat16*)outv)[(size_t)row * 256 + col] = __float2bfloat16(val);
    }
}

// ---------------------------------------------------------------------------
extern "C" void kernel_launch(void* const* d_in, const int* in_sizes, int n_in,
                              void* d_out, int out_size, void* d_ws, size_t ws_size,
                              hipStream_t stream) {
    const void* query     = d_in[0];
    const void* key       = d_in[1];
    const void* value     = d_in[2];
    const void* in_proj_w = d_in[3];
    const void* in_proj_b = d_in[4];
    const void* out_w     = d_in[5];
    const void* out_b     = d_in[6];
    const void* s_l_w     = d_in[7];
    const void* s_l_b     = d_in[8];
    const void* s_a_w     = d_in[9];
    const void* s_a_b     = d_in[10];
    const void* s_v_w     = d_in[11];
    const void* s_v_b     = d_in[12];
    const void* final_w   = d_in[13];
    const void* final_b   = d_in[14];

    float* ws     = (float*)d_ws;
    float* qws    = ws;                 //   786432 f
    float* kws    = ws + 786432;        //   786432 f
    float* vws    = ws + 1572864;       //   786432 f
    unsigned short* Ohi = (unsigned short*)(ws + 2359296);   // 5505024 bf16
    unsigned short* Olo = (unsigned short*)(ws + 5111808);   // 5505024 bf16
    float* Mtmp   = ws + 7864320;       //   458752 f
    unsigned short* DThi = (unsigned short*)(ws + 8323072);  // 458752 bf16
    unsigned short* DTlo = (unsigned short*)(ws + 8552448);  // 458752 bf16
    float* d0     = ws + 8781824;       //      256 f
    int*   flag   = (int*)(ws + 8782080);  // 1 int — proven footprint HIGH-WATER
    float* c0     = Mtmp;               // ALIAS: Mtmp dead after wcomb2

    detect_kernel<<<1, 64, 0, stream>>>((const unsigned short*)query, flag);
    qkv_gemm_kernel<<<dim3(12, 48), 256, 0, stream>>>(query, key, value,
                                                      in_proj_w, in_proj_b, flag,
                                                      qws, kws, vws);
    wcomb1_kernel<<<7 * 256, 256, 0, stream>>>(s_l_w, s_a_w, s_v_w, out_w, flag, Mtmp);
    attn_mfma_kernel<<<dim3(24, 32), 256, 0, stream>>>(qws, kws, vws, Ohi, Olo);
    wcomb2_gemm_kernel<<<dim3(4, 4, 7), 256, 0, stream>>>(Mtmp, final_w, flag,
                                                          DThi, DTlo);
    bias1_kernel<<<256, 256, 0, stream>>>(s_l_w, s_a_w, s_v_w, out_b,
                                          s_l_b, s_a_b, s_v_b, flag, c0);
    bias2_kernel<<<256, 256, 0, stream>>>(c0, final_w, final_b, flag, d0);
    final_gemm_mfma_kernel<<<dim3(4, 192), 256, 0, stream>>>(Ohi, Olo, DThi, DTlo,
                                                             d0, flag, d_out);
}

// Round 15
// 228.244 us; speedup vs baseline: 1.7694x; 1.0934x over previous
//
#include <hip/hip_runtime.h>
#include <hip/hip_bf16.h>

#define E 256
#define H 8
#define HD 32
#define T 768
#define B 4
#define BH 32
// segments: L=[0,300), A=[300,550), V=[550,768)

typedef __attribute__((ext_vector_type(8))) short bf16x8;
typedef __attribute__((ext_vector_type(4))) float f32x4;

__device__ __forceinline__ float b2f(__hip_bfloat16 x) { return __bfloat162float(x); }

__device__ __forceinline__ unsigned short f2bf_u(float x) {
    __hip_bfloat16 h = __float2bfloat16(x);
    return *(unsigned short*)&h;
}
__device__ __forceinline__ float bfu2f(unsigned short u) {
    return __uint_as_float(((unsigned int)u) << 16);
}

// split fp32[8] -> bf16 hi + lo fragments
__device__ __forceinline__ void f8_split(const float* v, bf16x8& h, bf16x8& l) {
    #pragma unroll
    for (int e = 0; e < 8; ++e) {
        unsigned short hu = f2bf_u(v[e]);
        h[e] = (short)hu;
        l[e] = (short)f2bf_u(v[e] - bfu2f(hu));
    }
}

#define MFMA3(ACC, AH, AL, BH_, BL_)                                         \
    ACC = __builtin_amdgcn_mfma_f32_16x16x32_bf16(AH, BH_, ACC, 0, 0, 0);    \
    ACC = __builtin_amdgcn_mfma_f32_16x16x32_bf16(AH, BL_, ACC, 0, 0, 0);    \
    ACC = __builtin_amdgcn_mfma_f32_16x16x32_bf16(AL, BH_, ACC, 0, 0, 0);

// dtype-agnostic scalar load: f32 ? float : bf16
__device__ __forceinline__ float ldu(const void* p, size_t i, int f32) {
    if (f32) return ((const float*)p)[i];
    return b2f(((const __hip_bfloat16*)p)[i]);
}

// ---------------------------------------------------------------------------
// Kernel 0: input dtype detection (fp32 read as bf16 -> garbage exponents).
// ---------------------------------------------------------------------------
__global__ void detect_kernel(const unsigned short* __restrict__ q,
                              int* __restrict__ flag) {
    if (threadIdx.x == 0 && blockIdx.x == 0) {
        int f32 = 0;
        for (int i = 0; i < 256; ++i) {
            unsigned int bits = ((unsigned int)q[i]) << 16;
            float v = __uint_as_float(bits);
            if (!(v == v) || fabsf(v) > 1e4f) f32 = 1;
        }
        *flag = f32;
    }
}

// ---------------------------------------------------------------------------
// Kernel 1: QKV projection (proven round-12 LDS-vectorized retile).
// ---------------------------------------------------------------------------
__global__ __launch_bounds__(256) void qkv_gemm_kernel(
    const void* query, const void* key, const void* value,
    const void* w, const void* bias, const int* __restrict__ flag,
    float* __restrict__ qws, float* __restrict__ kws, float* __restrict__ vws)
{
    int f32 = *flag;
    int bx = blockIdx.x;              // 0..11 col tiles
    int by = blockIdx.y;              // 0..47 row tiles
    int sec = bx >> 2;                // 0=q, 1=k, 2=v
    const void* X = (sec == 0) ? query : (sec == 1) ? key : value;
    int colbase = bx * 64;
    int rowbase = by * 64;
    int tid = threadIdx.x;
    int tx = tid & 15, ty = tid >> 4;
    __shared__ __align__(16) float AsT[32][68];   // [kk][row]
    __shared__ __align__(16) float Bs[32][68];    // [kk][col]
    float acc[4][4] = {};

    for (int kb = 0; kb < 8; ++kb) {
        __syncthreads();
        if (f32) {
            const float4* Xg = (const float4*)((const float*)X +
                                (size_t)rowbase * 256 + kb * 32);
            const float4* Wg = (const float4*)((const float*)w +
                                (size_t)colbase * 256 + kb * 32);
            #pragma unroll
            for (int l = 0; l < 2; ++l) {
                int idx4 = l * 256 + tid;
                int r = idx4 >> 3, kq = idx4 & 7;
                float4 xv = Xg[(size_t)r * 64 + kq];
                AsT[kq * 4 + 0][r] = xv.x;
                AsT[kq * 4 + 1][r] = xv.y;
                AsT[kq * 4 + 2][r] = xv.z;
                AsT[kq * 4 + 3][r] = xv.w;
                float4 wv = Wg[(size_t)r * 64 + kq];
                Bs[kq * 4 + 0][r] = wv.x;
                Bs[kq * 4 + 1][r] = wv.y;
                Bs[kq * 4 + 2][r] = wv.z;
                Bs[kq * 4 + 3][r] = wv.w;
            }
        } else {
            #pragma unroll
            for (int l = 0; l < 2; ++l) {
                int idx4 = l * 256 + tid;
                int r = idx4 >> 3, kq = idx4 & 7;
                #pragma unroll
                for (int j = 0; j < 4; ++j) {
                    AsT[kq * 4 + j][r] =
                        ldu(X, (size_t)(rowbase + r) * 256 + kb * 32 + kq * 4 + j, 0);
                    Bs[kq * 4 + j][r] =
                        ldu(w, (size_t)(colbase + r) * 256 + kb * 32 + kq * 4 + j, 0);
                }
            }
        }
        __syncthreads();
        #pragma unroll 8
        for (int kk = 0; kk < 32; ++kk) {
            const float4 av = *(const float4*)&AsT[kk][ty * 4];
            const float4 bv = *(const float4*)&Bs[kk][tx * 4];
            acc[0][0] += av.x * bv.x; acc[0][1] += av.x * bv.y;
            acc[0][2] += av.x * bv.z; acc[0][3] += av.x * bv.w;
            acc[1][0] += av.y * bv.x; acc[1][1] += av.y * bv.y;
            acc[1][2] += av.y * bv.z; acc[1][3] += av.y * bv.w;
            acc[2][0] += av.z * bv.x; acc[2][1] += av.z * bv.y;
            acc[2][2] += av.z * bv.z; acc[2][3] += av.z * bv.w;
            acc[3][0] += av.w * bv.x; acc[3][1] += av.w * bv.y;
            acc[3][2] += av.w * bv.z; acc[3][3] += av.w * bv.w;
        }
    }
    float* dst = (sec == 0) ? qws : (sec == 1) ? kws : vws;
    #pragma unroll
    for (int u = 0; u < 4; ++u)
        #pragma unroll
        for (int v = 0; v < 4; ++v) {
            int r = rowbase + ty * 4 + u;          // t*B + b
            int cg = colbase + tx * 4 + v;         // 0..767
            float val = acc[u][v] + ldu(bias, cg, f32);
            if (sec == 0) val *= 0.17677669529663687f;  // HD^-0.5
            int e_local = cg & 255;
            int h = e_local >> 5, hd = e_local & 31;
            int t = r >> 2, b = r & 3;
            dst[((size_t)((b * H + h) * T + t)) * HD + hd] = val;
        }
}

// ---------------------------------------------------------------------------
// Kernel 2 (proven round-14): MFMA attention.
// ---------------------------------------------------------------------------
__global__ __launch_bounds__(256) void attn_mfma_kernel(
    const float* __restrict__ qws, const float* __restrict__ kws,
    const float* __restrict__ vws,
    unsigned short* __restrict__ Ohi, unsigned short* __restrict__ Olo)
{
    int tile = blockIdx.x;       // 0..23
    int bh   = blockIdx.y;       // 0..31
    int t0 = tile * 32;
    int tid = threadIdx.x;
    int w = tid >> 6, lane = tid & 63;
    int m = lane & 15, quad = lane >> 4;
    int tb = w & 1, hdb = w >> 1;

    __shared__ __align__(16) unsigned short KFH[2048], KFL[2048];  // [4sb][64][8]
    __shared__ __align__(16) unsigned short VFH[2048], VFL[2048];  // [2hdb][2ks][64][8]
    __shared__ __align__(16) unsigned int   EPK[2048];             // [2tb][2ks][64][8]
    __shared__ float SP[4][16][3];
    __shared__ __align__(16) float PL[3 * 32 * 36];

    // q fragment (chunk-invariant, registers): A[m=t16][k=hd]
    bf16x8 aqh, aql;
    {
        const float* qr = qws + ((size_t)bh * T + t0 + tb * 16 + m) * HD + quad * 8;
        float qv[8];
        *(float4*)&qv[0] = *(const float4*)qr;
        *(float4*)&qv[4] = *(const float4*)(qr + 4);
        f8_split(qv, aqh, aql);
    }

    f32x4 acc0 = {}, acc1 = {}, acc2 = {};
    float ss0[4] = {}, ss1[4] = {}, ss2[4] = {};

    const float* kbase = kws + (size_t)bh * T * HD;
    const float* vbase = vws + (size_t)bh * T * HD;

    for (int ch = 0; ch < 12; ++ch) {
        int base = ch * 64;
        __syncthreads();
        // --- stage k fragments: slot (sb=tid>>6, lane) ---
        {
            int sb = tid >> 6, ln = tid & 63, km = ln & 15, kq = ln >> 4;
            const float* kr = kbase + (size_t)(base + sb * 16 + km) * HD + kq * 8;
            float kv[8];
            *(float4*)&kv[0] = *(const float4*)kr;
            *(float4*)&kv[4] = *(const float4*)(kr + 4);
            bf16x8 h, l;
            f8_split(kv, h, l);
            *(bf16x8*)&KFH[(sb * 64 + ln) * 8] = h;
            *(bf16x8*)&KFL[(sb * 64 + ln) * 8] = l;
        }
        // --- stage v fragments (transposed): slot (hdb=tid>>7, ks, lane) ---
        {
            int vh = tid >> 7, vks = (tid >> 6) & 1, vln = tid & 63;
            int vm = vln & 15, vq = vln >> 4;
            const float* vr = vbase + (size_t)(base + vks * 32 + vq * 8) * HD
                              + vh * 16 + vm;
            float vv[8];
            #pragma unroll
            for (int j = 0; j < 8; ++j) vv[j] = vr[(size_t)j * HD];
            bf16x8 h, l;
            f8_split(vv, h, l);
            *(bf16x8*)&VFH[((vh * 2 + vks) * 64 + vln) * 8] = h;
            *(bf16x8*)&VFL[((vh * 2 + vks) * 64 + vln) * 8] = l;
        }
        __syncthreads();

        // --- scores + exp + e_frag writes ---
        #pragma unroll
        for (int sbi = 0; sbi < 2; ++sbi) {
            int sb = (w >> 1) * 2 + sbi;
            bf16x8 bkh = *(const bf16x8*)&KFH[(sb * 64 + lane) * 8];
            bf16x8 bkl = *(const bf16x8*)&KFL[(sb * 64 + lane) * 8];
            f32x4 d = {};
            MFMA3(d, aqh, aql, bkh, bkl)
            int s64 = sb * 16 + m;           // s within chunk (C/D col)
            int sglob = base + s64;
            int ksw = s64 >> 5, qp = (s64 >> 3) & 3, jp = m & 7;
            unsigned int* eb = &EPK[(tb * 2 + ksw) * 512 + jp];
            #pragma unroll
            for (int r = 0; r < 4; ++r) {
                float e = __expf(d[r]);
                if (sglob < 300) ss0[r] += e;
                else if (sglob < 550) ss1[r] += e;
                else ss2[r] += e;
                unsigned short hu = f2bf_u(e);
                unsigned short lu = f2bf_u(e - bfu2f(hu));
                eb[((quad * 4 + r) + 16 * qp) * 8] =
                    (unsigned int)hu | ((unsigned int)lu << 16);
            }
        }
        __syncthreads();

        // --- PV: wave's (tb, hdb) tile, 2 k-steps ---
        #pragma unroll
        for (int ks = 0; ks < 2; ++ks) {
            const unsigned int* ep = &EPK[((tb * 2 + ks) * 64 + lane) * 8];
            uint4 p0 = *(const uint4*)ep;
            uint4 p1 = *(const uint4*)(ep + 4);
            bf16x8 aeh, ael;
            aeh[0] = (short)(p0.x & 0xffff); ael[0] = (short)(p0.x >> 16);
            aeh[1] = (short)(p0.y & 0xffff); ael[1] = (short)(p0.y >> 16);
            aeh[2] = (short)(p0.z & 0xffff); ael[2] = (short)(p0.z >> 16);
            aeh[3] = (short)(p0.w & 0xffff); ael[3] = (short)(p0.w >> 16);
            aeh[4] = (short)(p1.x & 0xffff); ael[4] = (short)(p1.x >> 16);
            aeh[5] = (short)(p1.y & 0xffff); ael[5] = (short)(p1.y >> 16);
            aeh[6] = (short)(p1.z & 0xffff); ael[6] = (short)(p1.z >> 16);
            aeh[7] = (short)(p1.w & 0xffff); ael[7] = (short)(p1.w >> 16);
            bf16x8 bvh = *(const bf16x8*)&VFH[((hdb * 2 + ks) * 64 + lane) * 8];
            bf16x8 bvl = *(const bf16x8*)&VFL[((hdb * 2 + ks) * 64 + lane) * 8];
            int s_lo = base + ks * 32;
            if (s_lo + 32 <= 300) { MFMA3(acc0, aeh, ael, bvh, bvl) }
            else if (s_lo >= 300 && s_lo + 32 <= 550) { MFMA3(acc1, aeh, ael, bvh, bvl) }
            else if (s_lo >= 550) { MFMA3(acc2, aeh, ael, bvh, bvl) }
            else {
                int bnd = (s_lo < 300) ? 300 : 550;
                bf16x8 eha = aeh, ela = ael, ehb = aeh, elb = ael;
                #pragma unroll
                for (int j = 0; j < 8; ++j) {
                    int s = s_lo + quad * 8 + j;
                    if (s < bnd) { ehb[j] = 0; elb[j] = 0; }
                    else         { eha[j] = 0; ela[j] = 0; }
                }
                if (s_lo < 300) { MFMA3(acc0, eha, ela, bvh, bvl)
                                  MFMA3(acc1, ehb, elb, bvh, bvl) }
                else            { MFMA3(acc1, eha, ela, bvh, bvl)
                                  MFMA3(acc2, ehb, elb, bvh, bvl) }
            }
        }
    }

    // S partials: reduce over the 16 s-lanes (width-16 shuffle), SP[w][t16][seg].
    #pragma unroll
    for (int sg = 0; sg < 3; ++sg)
        #pragma unroll
        for (int r = 0; r < 4; ++r) {
            float v = (sg == 0) ? ss0[r] : (sg == 1) ? ss1[r] : ss2[r];
            v += __shfl_down(v, 8, 16);
            v += __shfl_down(v, 4, 16);
            v += __shfl_down(v, 2, 16);
            v += __shfl_down(v, 1, 16);
            if (m == 0) SP[w][quad * 4 + r][sg] = v;
        }
    // P (C/D layout) -> PL[seg][t32][hd32] (stride 36)
    #pragma unroll
    for (int r = 0; r < 4; ++r) {
        int t32 = tb * 16 + quad * 4 + r;
        int hd = hdb * 16 + m;
        PL[0 * 1152 + t32 * 36 + hd] = acc0[r];
        PL[1 * 1152 + t32 * 36 + hd] = acc1[r];
        PL[2 * 1152 + t32 * 36 + hd] = acc2[r];
    }
    __syncthreads();

    // Epilogue (r13-proven): tt=t-row, q4=hd-quad; fragment-major O store.
    int tt = tid >> 3, q4 = tid & 7;
    float Pv[3][4];
    #pragma unroll
    for (int sg = 0; sg < 3; ++sg) {
        const float4 p = *(const float4*)&PL[sg * 1152 + tt * 36 + q4 * 4];
        Pv[sg][0] = p.x; Pv[sg][1] = p.y; Pv[sg][2] = p.z; Pv[sg][3] = p.w;
    }
    int tbe = tt >> 4, t16 = tt & 15;
    float S0 = SP[tbe][t16][0] + SP[tbe + 2][t16][0];
    float S1 = SP[tbe][t16][1] + SP[tbe + 2][t16][1];
    float S2 = SP[tbe][t16][2] + SP[tbe + 2][t16][2];

    int t_glob = t0 + tt;
    int g = (t_glob < 300) ? 0 : (t_glob < 550 ? 1 : 2);
    int b_ = bh >> 3, h_ = bh & 7;
    int row = t_glob * B + b_;
    int lslot = (row & 15) + ((q4 >> 1) << 4);
    int j0 = (q4 & 1) * 4;
    size_t fbase = (((size_t)(row >> 4) * 56 + h_) * 64 + lslot) * 8 + j0;
    const int masks[7] = {7, 3, 5, 6, 1, 2, 4};  // LAV,LA,LV,AV,L,A,V
    #pragma unroll
    for (int i = 0; i < 7; ++i) {
        int mm = masks[i];
        float n0 = 0.f, n1 = 0.f, n2 = 0.f, n3 = 0.f, den = 0.f;
        if (mm & 1) { n0 += Pv[0][0]; n1 += Pv[0][1]; n2 += Pv[0][2]; n3 += Pv[0][3]; den += S0; }
        if (mm & 2) { n0 += Pv[1][0]; n1 += Pv[1][1]; n2 += Pv[1][2]; n3 += Pv[1][3]; den += S1; }
        if (mm & 4) { n0 += Pv[2][0]; n1 += Pv[2][1]; n2 += Pv[2][2]; n3 += Pv[2][3]; den += S2; }
        float r = 1.f / den;
        int live = (mm >> g) & 1;
        float o[4];
        o[0] = live ? n0 * r : 0.f;
        o[1] = live ? n1 * r : 0.f;
        o[2] = live ? n2 * r : 0.f;
        o[3] = live ? n3 * r : 0.f;
        ushort4 hi4, lo4;
        unsigned short* hp = (unsigned short*)&hi4;
        unsigned short* lp = (unsigned short*)&lo4;
        #pragma unroll
        for (int j = 0; j < 4; ++j) {
            unsigned short hu = f2bf_u(o[j]);
            hp[j] = hu;
            lp[j] = f2bf_u(o[j] - bfu2f(hu));
        }
        size_t addr = fbase + (size_t)i * (8 * 64 * 8);
        *(ushort4*)&Ohi[addr] = hi4;
        *(ushort4*)&Olo[addr] = lo4;
    }
}

// ---------------------------------------------------------------------------
// Weight combination: D_i = (final_w @ G_i @ out_w[i])^T stacked as (1792,256).
// ---------------------------------------------------------------------------
__device__ __forceinline__ float gsum_load(int i, int r2, int r,
                                           const void* sl, const void* sa,
                                           const void* sv, int f32)
{
    size_t base = (size_t)r2 * 1024;
    switch (i) {
        case 0: return ldu(sl, base + r, f32) + ldu(sa, base + r, f32) + ldu(sv, base + r, f32);
        case 1: return ldu(sl, base + 256 + r, f32) + ldu(sa, base + 256 + r, f32);
        case 2: return ldu(sl, base + 512 + r, f32) + ldu(sv, base + 256 + r, f32);
        case 3: return ldu(sa, base + 512 + r, f32) + ldu(sv, base + 512 + r, f32);
        case 4: return ldu(sl, base + 768 + r, f32);
        case 5: return ldu(sa, base + 768 + r, f32);
        default: return ldu(sv, base + 768 + r, f32);
    }
}

// Mtmp_i = G_i @ out_w[i]    (proven round-2)
__global__ __launch_bounds__(256) void wcomb1_kernel(
    const void* sl, const void* sa, const void* sv, const void* outw,
    const int* __restrict__ flag, float* __restrict__ Mtmp)
{
    int f32 = *flag;
    int bid = blockIdx.x;
    int i = bid >> 8, r2 = bid & 255;
    int c = threadIdx.x;
    __shared__ float g[256];
    g[c] = gsum_load(i, r2, c, sl, sa, sv, f32);
    __syncthreads();
    float acc = 0.f;
    for (int r = 0; r < 256; ++r)
        acc += g[r] * ldu(outw, (size_t)i * 65536 + r * 256 + c, f32);
    Mtmp[(size_t)i * 65536 + r2 * 256 + c] = acc;
}

// DT hi/lo fragment-major (round-15 retile: 32x32 tiles, grid (8,8,7)=448
// blocks vs 112 — fixes 4.4% occupancy; inner loop now 2x b64 LDS per 4 FMA).
__global__ __launch_bounds__(256) void wcomb2_gemm_kernel(
    const float* __restrict__ Mtmp, const void* finalw,
    const int* __restrict__ flag,
    unsigned short* __restrict__ DThi, unsigned short* __restrict__ DTlo)
{
    int f32 = *flag;
    int bx = blockIdx.x;   // e tile 0..7 (32 cols)
    int by = blockIdx.y;   // c tile 0..7 (32 rows)
    int i  = blockIdx.z;   // branch 0..6
    int tid = threadIdx.x;
    int tx = tid & 15, ty = tid >> 4;
    int colbase = bx * 32, rowbase = by * 32;
    __shared__ __align__(16) float AsT[32][34];   // [kk][c]
    __shared__ __align__(16) float Bs[32][34];    // [kk][e]
    float acc[2][2] = {};

    for (int kb = 0; kb < 8; ++kb) {
        __syncthreads();
        #pragma unroll
        for (int l = 0; l < 4; ++l) {
            int idx = l * 256 + tid;
            int c = idx & 31, kk = idx >> 5;
            AsT[kk][c] = Mtmp[(size_t)i * 65536 + (kb * 32 + kk) * 256 + rowbase + c];
            int k2 = idx & 31, n = idx >> 5;
            Bs[k2][n] = ldu(finalw, (size_t)(colbase + n) * 256 + kb * 32 + k2, f32);
        }
        __syncthreads();
        #pragma unroll 8
        for (int kk = 0; kk < 32; ++kk) {
            const float2 av = *(const float2*)&AsT[kk][ty * 2];
            const float2 bv = *(const float2*)&Bs[kk][tx * 2];
            acc[0][0] += av.x * bv.x; acc[0][1] += av.x * bv.y;
            acc[1][0] += av.y * bv.x; acc[1][1] += av.y * bv.y;
        }
    }
    #pragma unroll
    for (int u = 0; u < 2; ++u)
        #pragma unroll
        for (int v = 0; v < 2; ++v) {
            int c = rowbase + ty * 2 + u, e = colbase + tx * 2 + v;
            float a = acc[u][v];
            unsigned short hu = f2bf_u(a);
            size_t fidx = (((size_t)(e >> 4) * 56 + i * 8 + (c >> 5)) * 64
                           + (e & 15) + (((c >> 3) & 3) << 4)) * 8 + (c & 7);
            DThi[fidx] = hu;
            DTlo[fidx] = f2bf_u(a - bfu2f(hu));
        }
}

// ---------------------------------------------------------------------------
// Bias path (proven round-5). c0 ALIASES Mtmp (dead after wcomb2).
// ---------------------------------------------------------------------------
__global__ __launch_bounds__(256) void bias1_kernel(
    const void* sl, const void* sa, const void* sv, const void* outb,
    const void* slb, const void* sab, const void* svb,
    const int* __restrict__ flag, float* __restrict__ c0)
{
    int f32 = *flag;
    int r2 = blockIdx.x, m = threadIdx.x;
    __shared__ float red[256];
    float acc = 0.f;
    #pragma unroll
    for (int i = 0; i < 7; ++i)
        acc += ldu(outb, i * 256 + m, f32) * gsum_load(i, r2, m, sl, sa, sv, f32);
    red[m] = acc;
    __syncthreads();
    for (int s = 128; s > 0; s >>= 1) {
        if (m < s) red[m] += red[m + s];
        __syncthreads();
    }
    if (m == 0)
        c0[r2] = red[0] + ldu(slb, r2, f32) + ldu(sab, r2, f32) + ldu(svb, r2, f32);
}

__global__ __launch_bounds__(256) void bias2_kernel(
    const float* __restrict__ c0, const void* finalw, const void* finalb,
    const int* __restrict__ flag, float* __restrict__ d0)
{
    int f32 = *flag;
    int e = blockIdx.x, r = threadIdx.x;
    __shared__ float red[256];
    red[r] = c0[r] * ldu(finalw, (size_t)e * 256 + r, f32);
    __syncthreads();
    for (int s = 128; s > 0; s >>= 1) {
        if (r < s) red[r] += red[r + s];
        __syncthreads();
    }
    if (r == 0)
        d0[e] = red[0] + ldu(finalb, e, f32);
}

// ---------------------------------------------------------------------------
// Kernel 4 (proven round-13, MFMA + fragment-major): result = O@Dstack + d0.
// ---------------------------------------------------------------------------
__global__ __launch_bounds__(256) void final_gemm_mfma_kernel(
    const unsigned short* __restrict__ Ohi, const unsigned short* __restrict__ Olo,
    const unsigned short* __restrict__ DThi, const unsigned short* __restrict__ DTlo,
    const float* __restrict__ d0, const int* __restrict__ flag,
    void* __restrict__ outv)
{
    int f32 = *flag;
    int bx = blockIdx.x;          // col group 0..3 (64 cols)
    int by = blockIdx.y;          // row group 0..191 (16 rows)
    int w  = threadIdx.x >> 6;    // wave 0..3
    int lane = threadIdx.x & 63;
    int m = lane & 15, quad = lane >> 4;
    int R0 = by * 16, C0 = bx * 64 + w * 16;

    int t0 = R0 >> 2, t1 = (R0 + 15) >> 2;
    int g0 = (t0 < 300) ? 0 : (t0 < 550 ? 1 : 2);
    int g1 = (t1 < 300) ? 0 : (t1 < 550 ? 1 : 2);
    int activeset = (1 << g0) | (1 << g1);
    const int masks[7] = {7, 3, 5, 6, 1, 2, 4};

    const unsigned short* Abase_h = Ohi + (size_t)by * 56 * 512 + lane * 8;
    const unsigned short* Abase_l = Olo + (size_t)by * 56 * 512 + lane * 8;
    const unsigned short* Bbase_h = DThi + (size_t)(bx * 4 + w) * 56 * 512 + lane * 8;
    const unsigned short* Bbase_l = DTlo + (size_t)(bx * 4 + w) * 56 * 512 + lane * 8;

    f32x4 acc = {};
    for (int i = 0; i < 7; ++i) {
        if (!(masks[i] & activeset)) continue;
        #pragma unroll
        for (int kb = 0; kb < 8; ++kb) {
            size_t off = (size_t)(i * 8 + kb) * 512;
            bf16x8 ah = *(const bf16x8*)(Abase_h + off);
            bf16x8 al = *(const bf16x8*)(Abase_l + off);
            bf16x8 bh = *(const bf16x8*)(Bbase_h + off);
            bf16x8 bl = *(const bf16x8*)(Bbase_l + off);
            acc = __builtin_amdgcn_mfma_f32_16x16x32_bf16(ah, bh, acc, 0, 0, 0);
            acc = __builtin_amdgcn_mfma_f32_16x16x32_bf16(ah, bl, acc, 0, 0, 0);
            acc = __builtin_amdgcn_mfma_f32_16x16x32_bf16(al, bh, acc, 0, 0, 0);
        }
    }
    float dv = d0[C0 + m];
    #pragma unroll
    for (int r = 0; r < 4; ++r) {
        int row = R0 + quad * 4 + r;
        int col = C0 + m;
        float val = acc[r] + dv;
        if (f32) ((float*)outv)[(size_t)row * 256 + col] = val;
        else ((__hip_bfloat16*)outv)[(size_t)row * 256 + col] = __float2bfloat16(val);
    }
}

// ---------------------------------------------------------------------------
extern "C" void kernel_launch(void* const* d_in, const int* in_sizes, int n_in,
                              void* d_out, int out_size, void* d_ws, size_t ws_size,
                              hipStream_t stream) {
    const void* query     = d_in[0];
    const void* key       = d_in[1];
    const void* value     = d_in[2];
    const void* in_proj_w = d_in[3];
    const void* in_proj_b = d_in[4];
    const void* out_w     = d_in[5];
    const void* out_b     = d_in[6];
    const void* s_l_w     = d_in[7];
    const void* s_l_b     = d_in[8];
    const void* s_a_w     = d_in[9];
    const void* s_a_b     = d_in[10];
    const void* s_v_w     = d_in[11];
    const void* s_v_b     = d_in[12];
    const void* final_w   = d_in[13];
    const void* final_b   = d_in[14];

    float* ws     = (float*)d_ws;
    float* qws    = ws;                 //   786432 f
    float* kws    = ws + 786432;        //   786432 f
    float* vws    = ws + 1572864;       //   786432 f
    unsigned short* Ohi = (unsigned short*)(ws + 2359296);   // 5505024 bf16
    unsigned short* Olo = (unsigned short*)(ws + 5111808);   // 5505024 bf16
    float* Mtmp   = ws + 7864320;       //   458752 f
    unsigned short* DThi = (unsigned short*)(ws + 8323072);  // 458752 bf16
    unsigned short* DTlo = (unsigned short*)(ws + 8552448);  // 458752 bf16
    float* d0     = ws + 8781824;       //      256 f
    int*   flag   = (int*)(ws + 8782080);  // 1 int — proven footprint HIGH-WATER
    float* c0     = Mtmp;               // ALIAS: Mtmp dead after wcomb2

    detect_kernel<<<1, 64, 0, stream>>>((const unsigned short*)query, flag);
    qkv_gemm_kernel<<<dim3(12, 48), 256, 0, stream>>>(query, key, value,
                                                      in_proj_w, in_proj_b, flag,
                                                      qws, kws, vws);
    wcomb1_kernel<<<7 * 256, 256, 0, stream>>>(s_l_w, s_a_w, s_v_w, out_w, flag, Mtmp);
    attn_mfma_kernel<<<dim3(24, 32), 256, 0, stream>>>(qws, kws, vws, Ohi, Olo);
    wcomb2_gemm_kernel<<<dim3(8, 8, 7), 256, 0, stream>>>(Mtmp, final_w, flag,
                                                          DThi, DTlo);
    bias1_kernel<<<256, 256, 0, stream>>>(s_l_w, s_a_w, s_v_w, out_b,
                                          s_l_b, s_a_b, s_v_b, flag, c0);
    bias2_kernel<<<256, 256, 0, stream>>>(c0, final_w, final_b, flag, d0);
    final_gemm_mfma_kernel<<<dim3(4, 192), 256, 0, stream>>>(Ohi, Olo, DThi, DTlo,
                                                             d0, flag, d_out);
}